// Round 3
// baseline (409.676 us; speedup 1.0000x reference)
//
#include <hip/hip_runtime.h>
#include <math.h>

#define N_NODES 50000
#define N_EDGES 800000
#define D 64
#define N_GRAPHS 512
#define N_LAYERS 3
#define HID_FC 64
#define N_CLASSES 10

#define SCAN_B 512
#define NB_SCAN ((N_NODES + SCAN_B - 1) / SCAN_B)  // 98

// ---------------- helpers ----------------

__device__ __forceinline__ unsigned mapf(float f) {
  unsigned u = __float_as_uint(f);
  return (u & 0x80000000u) ? ~u : (u | 0x80000000u);
}
__device__ __forceinline__ float unmapf(unsigned u) {
  return __uint_as_float((u & 0x80000000u) ? (u & 0x7FFFFFFFu) : ~u);
}

// pack two f32 -> (bf16,bf16) in one uint, RNE rounding
__device__ __forceinline__ unsigned pack2(float a, float b) {
  unsigned ua = __float_as_uint(a);
  unsigned ub = __float_as_uint(b);
  ua += 0x7FFFu + ((ua >> 16) & 1u);
  ub += 0x7FFFu + ((ub >> 16) & 1u);
  return (ua >> 16) | (ub & 0xFFFF0000u);
}
__device__ __forceinline__ float2 unpack2(unsigned v) {
  return make_float2(__uint_as_float(v << 16), __uint_as_float(v & 0xFFFF0000u));
}

// ---------------- x -> bf16 ----------------

__global__ void to_bf16(const float* __restrict__ in, unsigned* __restrict__ out) {
  int i = blockIdx.x * 256 + threadIdx.x;  // one float4 -> uint2 per thread
  float4 v = reinterpret_cast<const float4*>(in)[i];
  reinterpret_cast<uint2*>(out)[i] = make_uint2(pack2(v.x, v.y), pack2(v.z, v.w));
}

// ---------------- CSR build ----------------

__global__ void hist_kernel(const int* __restrict__ dst, int* __restrict__ deg) {
  int e = blockIdx.x * 256 + threadIdx.x;
  if (e < N_EDGES) atomicAdd(&deg[dst[e]], 1);
}

__global__ void scan_blocks(const int* __restrict__ deg, int* __restrict__ bsum) {
  __shared__ int sd[SCAN_B];
  int i = blockIdx.x * SCAN_B + threadIdx.x;
  sd[threadIdx.x] = (i < N_NODES) ? deg[i] : 0;
  __syncthreads();
  for (int off = SCAN_B / 2; off > 0; off >>= 1) {
    if (threadIdx.x < off) sd[threadIdx.x] += sd[threadIdx.x + off];
    __syncthreads();
  }
  if (threadIdx.x == 0) bsum[blockIdx.x] = sd[0];
}

__global__ void scan_mid(int* __restrict__ bsum) {
  __shared__ int s[256];
  int t = threadIdx.x;
  if (t < NB_SCAN) s[t] = bsum[t];
  __syncthreads();
  if (t == 0) {
    int run = 0;
    for (int i = 0; i < NB_SCAN; ++i) { int v = s[i]; s[i] = run; run += v; }
  }
  __syncthreads();
  if (t < NB_SCAN) bsum[t] = s[t];
}

__global__ void scan_final(const int* __restrict__ deg, const int* __restrict__ bsum,
                           int* __restrict__ rs, int* __restrict__ cur) {
  __shared__ int sd[SCAN_B];
  int i = blockIdx.x * SCAN_B + threadIdx.x;
  int v = (i < N_NODES) ? deg[i] : 0;
  sd[threadIdx.x] = v;
  __syncthreads();
  for (int off = 1; off < SCAN_B; off <<= 1) {
    int add = (threadIdx.x >= off) ? sd[threadIdx.x - off] : 0;
    __syncthreads();
    sd[threadIdx.x] += add;
    __syncthreads();
  }
  if (i < N_NODES) {
    int ex = bsum[blockIdx.x] + sd[threadIdx.x] - v;
    rs[i] = ex;
    cur[i] = ex;
  }
  if (i == 0) rs[N_NODES] = N_EDGES;
}

__global__ void fill_csr(const int* __restrict__ src, const int* __restrict__ dst,
                         int* __restrict__ cur, int* __restrict__ csr) {
  int e = blockIdx.x * 256 + threadIdx.x;
  if (e >= N_EDGES) return;
  int p = atomicAdd(&cur[dst[e]], 1);
  csr[p] = src[e];
}

// ---------------- fused layer: agg (gather) + MLP (+ final pooling) ----------------
// hin: bf16 rows (32 uints per node). FINAL==0: write bf16 rows to hout.
// FINAL==1: atomicMax into gU instead of writing h.

template <int FINAL>
__global__ __launch_bounds__(256) void layer_kernel(
    const unsigned* __restrict__ hin,
    const int* __restrict__ csr, const int* __restrict__ rs,
    const float* __restrict__ W1, const float* __restrict__ b1,
    const float* __restrict__ W2, const float* __restrict__ b2,
    unsigned* __restrict__ hout,
    const int* __restrict__ batch, unsigned* __restrict__ gU) {
  __shared__ float W1s[64 * 64];
  __shared__ float W2s[64 * 64];
  __shared__ float As[16][68];
  __shared__ float Hs[16][68];
  const int t = threadIdx.x;
  const int base = blockIdx.x * 16;

  // stage weights
  {
    const float4* w1v = (const float4*)W1;
    const float4* w2v = (const float4*)W2;
    float4* w1s = (float4*)W1s;
    float4* w2s = (float4*)W2s;
#pragma unroll
    for (int i = 0; i < 4; ++i) {
      w1s[t + 256 * i] = w1v[t + 256 * i];
      w2s[t + 256 * i] = w2v[t + 256 * i];
    }
  }

  // ---- gather phase: wave w handles nodes base+w*4 .. base+w*4+3 ----
  {
    const int w = t >> 6, lane = t & 63, half = lane >> 5, hl = lane & 31;
#pragma unroll
    for (int i = 0; i < 4; ++i) {
      const int r = w * 4 + i;
      const int node = base + r;
      const int e0 = rs[node], e1 = rs[node + 1];
      float ax = 0.0f, ay = 0.0f;
      if (!half) {  // self term
        float2 s = unpack2(hin[node * 32 + hl]);
        ax = s.x; ay = s.y;
      }
      int e = e0 + half;  // half 0: even slots, half 1: odd slots
      for (; e + 2 < e1; e += 4) {
        int sA = csr[e], sB = csr[e + 2];
        float2 vA = unpack2(hin[sA * 32 + hl]);
        float2 vB = unpack2(hin[sB * 32 + hl]);
        ax += vA.x; ay += vA.y;
        ax += vB.x; ay += vB.y;
      }
      for (; e < e1; e += 2) {
        int s = csr[e];
        float2 v = unpack2(hin[s * 32 + hl]);
        ax += v.x; ay += v.y;
      }
      ax += __shfl_xor(ax, 32);
      ay += __shfl_xor(ay, 32);
      if (!half) {
        As[r][2 * hl] = ax;
        As[r][2 * hl + 1] = ay;
      }
    }
  }
  __syncthreads();

  // ---- MLP phase: 16 threads per row, 4 outputs each ----
  const int r = t >> 4, cg = t & 15;
  float4 bb = ((const float4*)b1)[cg];
  float a0 = bb.x, a1 = bb.y, a2 = bb.z, a3 = bb.w;
#pragma unroll
  for (int k = 0; k < 64; ++k) {
    float x = As[r][k];
    float4 wv = *(const float4*)&W1s[k * 64 + cg * 4];
    a0 = fmaf(x, wv.x, a0);
    a1 = fmaf(x, wv.y, a1);
    a2 = fmaf(x, wv.z, a2);
    a3 = fmaf(x, wv.w, a3);
  }
  Hs[r][cg * 4 + 0] = fmaxf(a0, 0.0f);
  Hs[r][cg * 4 + 1] = fmaxf(a1, 0.0f);
  Hs[r][cg * 4 + 2] = fmaxf(a2, 0.0f);
  Hs[r][cg * 4 + 3] = fmaxf(a3, 0.0f);
  __syncthreads();

  bb = ((const float4*)b2)[cg];
  a0 = bb.x; a1 = bb.y; a2 = bb.z; a3 = bb.w;
#pragma unroll
  for (int k = 0; k < 64; ++k) {
    float x = Hs[r][k];
    float4 wv = *(const float4*)&W2s[k * 64 + cg * 4];
    a0 = fmaf(x, wv.x, a0);
    a1 = fmaf(x, wv.y, a1);
    a2 = fmaf(x, wv.z, a2);
    a3 = fmaf(x, wv.w, a3);
  }

  const int row = base + r;
  if (FINAL) {
    const int g = batch[row];
    atomicMax(&gU[g * 64 + cg * 4 + 0], mapf(a0));
    atomicMax(&gU[g * 64 + cg * 4 + 1], mapf(a1));
    atomicMax(&gU[g * 64 + cg * 4 + 2], mapf(a2));
    atomicMax(&gU[g * 64 + cg * 4 + 3], mapf(a3));
  } else {
    reinterpret_cast<uint2*>(hout)[row * 16 + cg] =
        make_uint2(pack2(a0, a1), pack2(a2, a3));
  }
}

// ---------------- pooling init + head ----------------

__global__ void init_g(unsigned* __restrict__ gU) {
  int i = blockIdx.x * blockDim.x + threadIdx.x;
  if (i < N_GRAPHS * D) gU[i] = 0x007FFFFFu;  // mapf(-inf)
}

__global__ void head_kernel(const unsigned* __restrict__ gU,
                            const float* __restrict__ fcW1, const float* __restrict__ fcb1,
                            const float* __restrict__ fcW2, const float* __restrict__ fcb2,
                            float* __restrict__ out) {
  __shared__ float g[64];
  __shared__ float hid[64];
  __shared__ float logit[N_CLASSES];
  __shared__ float red[2];
  const int gi = blockIdx.x;
  const int t = threadIdx.x;

  g[t] = unmapf(gU[gi * D + t]);
  __syncthreads();

  float a = fcb1[t];
#pragma unroll
  for (int k = 0; k < 64; ++k) a = fmaf(g[k], fcW1[k * HID_FC + t], a);
  hid[t] = fmaxf(a, 0.0f);
  __syncthreads();

  if (t < N_CLASSES) {
    float l = fcb2[t];
#pragma unroll
    for (int k = 0; k < 64; ++k) l = fmaf(hid[k], fcW2[k * N_CLASSES + t], l);
    logit[t] = l;
  }
  __syncthreads();

  if (t == 0) {
    float m = logit[0];
    for (int i = 1; i < N_CLASSES; ++i) m = fmaxf(m, logit[i]);
    float s = 0.0f;
    for (int i = 0; i < N_CLASSES; ++i) s += expf(logit[i] - m);
    red[0] = m;
    red[1] = logf(s);
  }
  __syncthreads();

  if (t < N_CLASSES) out[gi * N_CLASSES + t] = logit[t] - red[0] - red[1];
}

// ---------------- launch ----------------

extern "C" void kernel_launch(void* const* d_in, const int* in_sizes, int n_in,
                              void* d_out, int out_size, void* d_ws, size_t ws_size,
                              hipStream_t stream) {
  const float* x      = (const float*)d_in[0];
  const float* convW1 = (const float*)d_in[1];
  const float* convb1 = (const float*)d_in[2];
  const float* convW2 = (const float*)d_in[3];
  const float* convb2 = (const float*)d_in[4];
  const float* fcW1   = (const float*)d_in[5];
  const float* fcb1   = (const float*)d_in[6];
  const float* fcW2   = (const float*)d_in[7];
  const float* fcb2   = (const float*)d_in[8];
  const int*   edge   = (const int*)d_in[9];
  const int*   batch  = (const int*)d_in[10];
  float* out = (float*)d_out;

  const int* src = edge;
  const int* dst = edge + N_EDGES;

  // workspace layout (uints/ints)
  unsigned* xb  = (unsigned*)d_ws;                  // 50000*32 uints (bf16 x)
  unsigned* hbA = xb + (size_t)N_NODES * 32;        // 50000*32
  unsigned* hbB = hbA + (size_t)N_NODES * 32;       // 50000*32
  unsigned* gU  = hbB + (size_t)N_NODES * 32;       // 512*64
  int* deg  = (int*)(gU + N_GRAPHS * D);
  int* rs   = deg + N_NODES;
  int* cur  = rs + N_NODES + 1;
  int* bsum = cur + N_NODES;
  int* csr  = bsum + 256;

  // ---- x -> bf16 (3.2M elems, 800k float4 groups) ----
  to_bf16<<<(N_NODES * 16) / 256, 256, 0, stream>>>(x, xb);
  init_g<<<(N_GRAPHS * D + 255) / 256, 256, 0, stream>>>(gU);

  // ---- CSR build (dst-indexed) ----
  hipMemsetAsync(deg, 0, N_NODES * sizeof(int), stream);
  hist_kernel<<<N_EDGES / 256, 256, 0, stream>>>(dst, deg);
  scan_blocks<<<NB_SCAN, SCAN_B, 0, stream>>>(deg, bsum);
  scan_mid<<<1, 256, 0, stream>>>(bsum);
  scan_final<<<NB_SCAN, SCAN_B, 0, stream>>>(deg, bsum, rs, cur);
  fill_csr<<<N_EDGES / 256, 256, 0, stream>>>(src, dst, cur, csr);

  // ---- 3 fused GIN layers ----
  const int NBLK = N_NODES / 16;  // 3125
  layer_kernel<0><<<NBLK, 256, 0, stream>>>(
      xb, csr, rs, convW1, convb1, convW2, convb2, hbA, batch, gU);
  layer_kernel<0><<<NBLK, 256, 0, stream>>>(
      hbA, csr, rs, convW1 + D * D, convb1 + D, convW2 + D * D, convb2 + D, hbB, batch, gU);
  layer_kernel<1><<<NBLK, 256, 0, stream>>>(
      hbB, csr, rs, convW1 + 2 * D * D, convb1 + 2 * D, convW2 + 2 * D * D, convb2 + 2 * D,
      nullptr, batch, gU);

  // ---- FC head + log_softmax ----
  head_kernel<<<N_GRAPHS, 64, 0, stream>>>(gU, fcW1, fcb1, fcW2, fcb2, out);
}

// Round 4
// 285.604 us; speedup vs baseline: 1.4344x; 1.4344x over previous
//
#include <hip/hip_runtime.h>
#include <math.h>

#define N_NODES 50000
#define N_EDGES 800000
#define D 64
#define N_GRAPHS 512
#define N_LAYERS 3
#define HID_FC 64
#define N_CLASSES 10

#define SCAN_B 512
#define NB_SCAN ((N_NODES + SCAN_B - 1) / SCAN_B)  // 98

// ---------------- helpers ----------------

__device__ __forceinline__ unsigned mapf(float f) {
  unsigned u = __float_as_uint(f);
  return (u & 0x80000000u) ? ~u : (u | 0x80000000u);
}
__device__ __forceinline__ float unmapf(unsigned u) {
  return __uint_as_float((u & 0x80000000u) ? (u & 0x7FFFFFFFu) : ~u);
}

// pack two f32 -> (bf16,bf16) in one uint, RNE
__device__ __forceinline__ unsigned pack2(float a, float b) {
  unsigned ua = __float_as_uint(a);
  unsigned ub = __float_as_uint(b);
  ua += 0x7FFFu + ((ua >> 16) & 1u);
  ub += 0x7FFFu + ((ub >> 16) & 1u);
  return (ua >> 16) | (ub & 0xFFFF0000u);
}
__device__ __forceinline__ float2 unpack2(unsigned v) {
  return make_float2(__uint_as_float(v << 16), __uint_as_float(v & 0xFFFF0000u));
}

// ---------------- x -> bf16 ----------------

__global__ void to_bf16(const float* __restrict__ in, unsigned* __restrict__ out) {
  int i = blockIdx.x * 256 + threadIdx.x;  // one float4 -> uint2 per thread
  float4 v = reinterpret_cast<const float4*>(in)[i];
  reinterpret_cast<uint2*>(out)[i] = make_uint2(pack2(v.x, v.y), pack2(v.z, v.w));
}

// ---------------- CSR build ----------------

__global__ void hist_kernel(const int* __restrict__ dst, int* __restrict__ deg) {
  int e = blockIdx.x * 256 + threadIdx.x;
  if (e < N_EDGES) atomicAdd(&deg[dst[e]], 1);
}

__global__ void scan_blocks(const int* __restrict__ deg, int* __restrict__ bsum) {
  __shared__ int sd[SCAN_B];
  int i = blockIdx.x * SCAN_B + threadIdx.x;
  sd[threadIdx.x] = (i < N_NODES) ? deg[i] : 0;
  __syncthreads();
  for (int off = SCAN_B / 2; off > 0; off >>= 1) {
    if (threadIdx.x < off) sd[threadIdx.x] += sd[threadIdx.x + off];
    __syncthreads();
  }
  if (threadIdx.x == 0) bsum[blockIdx.x] = sd[0];
}

__global__ void scan_mid(int* __restrict__ bsum) {
  __shared__ int s[256];
  int t = threadIdx.x;
  if (t < NB_SCAN) s[t] = bsum[t];
  __syncthreads();
  if (t == 0) {
    int run = 0;
    for (int i = 0; i < NB_SCAN; ++i) { int v = s[i]; s[i] = run; run += v; }
  }
  __syncthreads();
  if (t < NB_SCAN) bsum[t] = s[t];
}

__global__ void scan_final(const int* __restrict__ deg, const int* __restrict__ bsum,
                           int* __restrict__ rs, int* __restrict__ cur) {
  __shared__ int sd[SCAN_B];
  int i = blockIdx.x * SCAN_B + threadIdx.x;
  int v = (i < N_NODES) ? deg[i] : 0;
  sd[threadIdx.x] = v;
  __syncthreads();
  for (int off = 1; off < SCAN_B; off <<= 1) {
    int add = (threadIdx.x >= off) ? sd[threadIdx.x - off] : 0;
    __syncthreads();
    sd[threadIdx.x] += add;
    __syncthreads();
  }
  if (i < N_NODES) {
    int ex = bsum[blockIdx.x] + sd[threadIdx.x] - v;
    rs[i] = ex;
    cur[i] = ex;
  }
  if (i == 0) rs[N_NODES] = N_EDGES;
}

__global__ void fill_csr(const int* __restrict__ src, const int* __restrict__ dst,
                         int* __restrict__ cur, int* __restrict__ csr) {
  int e = blockIdx.x * 256 + threadIdx.x;
  if (e >= N_EDGES) return;
  int p = atomicAdd(&cur[dst[e]], 1);
  csr[p] = src[e];
}

// ---------------- GIN aggregation: acc[n] = h[n] + sum_{e} h[csr[e]] ----------------
// hin: bf16 rows (32 uints/node). acc: f32 rows. Half-wave (32 lanes) per node.

__global__ __launch_bounds__(256) void agg_bf16(
    const unsigned* __restrict__ hin, const int* __restrict__ csr,
    const int* __restrict__ rs, float* __restrict__ acc) {
  const int t = threadIdx.x;
  const int hw = t >> 5;   // half-wave 0..7
  const int hl = t & 31;
  const int node = blockIdx.x * 8 + hw;
  float2 a = unpack2(hin[node * 32 + hl]);  // self term
  int e = rs[node];
  const int e1 = rs[node + 1];
  for (; e + 4 <= e1; e += 4) {
    int s0 = csr[e], s1 = csr[e + 1], s2 = csr[e + 2], s3 = csr[e + 3];
    float2 v0 = unpack2(hin[s0 * 32 + hl]);
    float2 v1 = unpack2(hin[s1 * 32 + hl]);
    float2 v2 = unpack2(hin[s2 * 32 + hl]);
    float2 v3 = unpack2(hin[s3 * 32 + hl]);
    a.x += v0.x + v1.x; a.y += v0.y + v1.y;
    a.x += v2.x + v3.x; a.y += v2.y + v3.y;
  }
  for (; e < e1; ++e) {
    float2 v = unpack2(hin[csr[e] * 32 + hl]);
    a.x += v.x; a.y += v.y;
  }
  reinterpret_cast<float2*>(acc)[node * 32 + hl] = a;
}

// ---------------- per-layer MLP: h = relu(A@W1+b1)@W2+b2 ----------------
// A: f32 [N][64]. FINAL==0: write bf16 rows to hout. FINAL==1: atomicMax into gU.
// Single 16KB W buffer staged twice -> 25KB LDS -> 6 blocks/CU.

template <int FINAL>
__global__ __launch_bounds__(256) void mlp64(
    const float* __restrict__ A,
    const float* __restrict__ W1, const float* __restrict__ b1,
    const float* __restrict__ W2, const float* __restrict__ b2,
    unsigned* __restrict__ hout,
    const int* __restrict__ batch, unsigned* __restrict__ gU) {
  __shared__ float Ws[64 * 64];
  __shared__ float As[16][68];
  __shared__ float Hs[16][68];
  const int t = threadIdx.x;
  const int r = t >> 4, cg = t & 15;
  const int row = blockIdx.x * 16 + r;

  {
    float4* ws = (float4*)Ws;
    const float4* wv = (const float4*)W1;
#pragma unroll
    for (int i = 0; i < 4; ++i) ws[t + 256 * i] = wv[t + 256 * i];
  }
  *(float4*)&As[r][cg * 4] = ((const float4*)(A + (size_t)row * 64))[cg];
  __syncthreads();

  float4 bb = ((const float4*)b1)[cg];
  float a0 = bb.x, a1 = bb.y, a2 = bb.z, a3 = bb.w;
#pragma unroll
  for (int k = 0; k < 64; ++k) {
    float x = As[r][k];
    float4 w = *(const float4*)&Ws[k * 64 + cg * 4];
    a0 = fmaf(x, w.x, a0);
    a1 = fmaf(x, w.y, a1);
    a2 = fmaf(x, w.z, a2);
    a3 = fmaf(x, w.w, a3);
  }
  Hs[r][cg * 4 + 0] = fmaxf(a0, 0.0f);
  Hs[r][cg * 4 + 1] = fmaxf(a1, 0.0f);
  Hs[r][cg * 4 + 2] = fmaxf(a2, 0.0f);
  Hs[r][cg * 4 + 3] = fmaxf(a3, 0.0f);
  __syncthreads();  // all GEMM1 reads of Ws done

  {
    float4* ws = (float4*)Ws;
    const float4* wv = (const float4*)W2;
#pragma unroll
    for (int i = 0; i < 4; ++i) ws[t + 256 * i] = wv[t + 256 * i];
  }
  __syncthreads();

  bb = ((const float4*)b2)[cg];
  a0 = bb.x; a1 = bb.y; a2 = bb.z; a3 = bb.w;
#pragma unroll
  for (int k = 0; k < 64; ++k) {
    float x = Hs[r][k];
    float4 w = *(const float4*)&Ws[k * 64 + cg * 4];
    a0 = fmaf(x, w.x, a0);
    a1 = fmaf(x, w.y, a1);
    a2 = fmaf(x, w.z, a2);
    a3 = fmaf(x, w.w, a3);
  }

  if (FINAL) {
    const int g = batch[row];
    atomicMax(&gU[g * 64 + cg * 4 + 0], mapf(a0));
    atomicMax(&gU[g * 64 + cg * 4 + 1], mapf(a1));
    atomicMax(&gU[g * 64 + cg * 4 + 2], mapf(a2));
    atomicMax(&gU[g * 64 + cg * 4 + 3], mapf(a3));
  } else {
    reinterpret_cast<uint2*>(hout)[row * 16 + cg] =
        make_uint2(pack2(a0, a1), pack2(a2, a3));
  }
}

// ---------------- pooling init + head ----------------

__global__ void init_g(unsigned* __restrict__ gU) {
  int i = blockIdx.x * blockDim.x + threadIdx.x;
  if (i < N_GRAPHS * D) gU[i] = 0x007FFFFFu;  // mapf(-inf)
}

__global__ void head_kernel(const unsigned* __restrict__ gU,
                            const float* __restrict__ fcW1, const float* __restrict__ fcb1,
                            const float* __restrict__ fcW2, const float* __restrict__ fcb2,
                            float* __restrict__ out) {
  __shared__ float g[64];
  __shared__ float hid[64];
  __shared__ float logit[N_CLASSES];
  __shared__ float red[2];
  const int gi = blockIdx.x;
  const int t = threadIdx.x;

  g[t] = unmapf(gU[gi * D + t]);
  __syncthreads();

  float a = fcb1[t];
#pragma unroll
  for (int k = 0; k < 64; ++k) a = fmaf(g[k], fcW1[k * HID_FC + t], a);
  hid[t] = fmaxf(a, 0.0f);
  __syncthreads();

  if (t < N_CLASSES) {
    float l = fcb2[t];
#pragma unroll
    for (int k = 0; k < 64; ++k) l = fmaf(hid[k], fcW2[k * N_CLASSES + t], l);
    logit[t] = l;
  }
  __syncthreads();

  if (t == 0) {
    float m = logit[0];
    for (int i = 1; i < N_CLASSES; ++i) m = fmaxf(m, logit[i]);
    float s = 0.0f;
    for (int i = 0; i < N_CLASSES; ++i) s += expf(logit[i] - m);
    red[0] = m;
    red[1] = logf(s);
  }
  __syncthreads();

  if (t < N_CLASSES) out[gi * N_CLASSES + t] = logit[t] - red[0] - red[1];
}

// ---------------- launch ----------------

extern "C" void kernel_launch(void* const* d_in, const int* in_sizes, int n_in,
                              void* d_out, int out_size, void* d_ws, size_t ws_size,
                              hipStream_t stream) {
  const float* x      = (const float*)d_in[0];
  const float* convW1 = (const float*)d_in[1];
  const float* convb1 = (const float*)d_in[2];
  const float* convW2 = (const float*)d_in[3];
  const float* convb2 = (const float*)d_in[4];
  const float* fcW1   = (const float*)d_in[5];
  const float* fcb1   = (const float*)d_in[6];
  const float* fcW2   = (const float*)d_in[7];
  const float* fcb2   = (const float*)d_in[8];
  const int*   edge   = (const int*)d_in[9];
  const int*   batch  = (const int*)d_in[10];
  float* out = (float*)d_out;

  const int* src = edge;
  const int* dst = edge + N_EDGES;

  // workspace layout (29.1 MB; 29.5 MB proven safe in round 2)
  unsigned* xb  = (unsigned*)d_ws;                    // 6.4 MB (h0, also reused for h2)
  unsigned* hbA = xb + (size_t)N_NODES * 32;          // 6.4 MB (h1)
  float*    acc = (float*)(hbA + (size_t)N_NODES * 32);  // 12.8 MB f32 agg
  unsigned* gU  = (unsigned*)(acc + (size_t)N_NODES * 64);  // 131 KB
  int* rs  = (int*)(gU + N_GRAPHS * D);               // 200 KB (persists)
  int* csr = rs + N_NODES + 1;                        // 3.2 MB
  // deg/cur/bsum live inside acc's region (dead before acc is first written)
  int* deg  = (int*)acc;
  int* cur  = deg + N_NODES;
  int* bsum = cur + N_NODES;

  // ---- x -> bf16 + pool init ----
  to_bf16<<<(N_NODES * 16) / 256, 256, 0, stream>>>(x, xb);
  init_g<<<(N_GRAPHS * D + 255) / 256, 256, 0, stream>>>(gU);

  // ---- CSR build (dst-indexed) ----
  hipMemsetAsync(deg, 0, N_NODES * sizeof(int), stream);
  hist_kernel<<<N_EDGES / 256, 256, 0, stream>>>(dst, deg);
  scan_blocks<<<NB_SCAN, SCAN_B, 0, stream>>>(deg, bsum);
  scan_mid<<<1, 256, 0, stream>>>(bsum);
  scan_final<<<NB_SCAN, SCAN_B, 0, stream>>>(deg, bsum, rs, cur);
  fill_csr<<<N_EDGES / 256, 256, 0, stream>>>(src, dst, cur, csr);

  // ---- 3 GIN layers: agg (gather, f32 out) + MLP ----
  const int AGG_B = N_NODES / 8;    // 6250
  const int MLP_B = N_NODES / 16;   // 3125
  agg_bf16<<<AGG_B, 256, 0, stream>>>(xb, csr, rs, acc);
  mlp64<0><<<MLP_B, 256, 0, stream>>>(acc, convW1, convb1, convW2, convb2,
                                      hbA, batch, gU);
  agg_bf16<<<AGG_B, 256, 0, stream>>>(hbA, csr, rs, acc);
  mlp64<0><<<MLP_B, 256, 0, stream>>>(acc, convW1 + D * D, convb1 + D,
                                      convW2 + D * D, convb2 + D, xb, batch, gU);
  agg_bf16<<<AGG_B, 256, 0, stream>>>(xb, csr, rs, acc);
  mlp64<1><<<MLP_B, 256, 0, stream>>>(acc, convW1 + 2 * D * D, convb1 + 2 * D,
                                      convW2 + 2 * D * D, convb2 + 2 * D,
                                      nullptr, batch, gU);

  // ---- FC head + log_softmax ----
  head_kernel<<<N_GRAPHS, 64, 0, stream>>>(gU, fcW1, fcb1, fcW2, fcb2, out);
}

// Round 5
// 278.024 us; speedup vs baseline: 1.4735x; 1.0273x over previous
//
#include <hip/hip_runtime.h>
#include <math.h>

#define N_NODES 50000
#define N_EDGES 800000
#define D 64
#define N_GRAPHS 512
#define N_CLASSES 10
#define NT 3125  // 16-row tiles

#define SCAN_B 512
#define NB_SCAN ((N_NODES + SCAN_B - 1) / SCAN_B)  // 98

typedef __attribute__((ext_vector_type(8))) short bf16x8;
typedef __attribute__((ext_vector_type(4))) float f32x4;

#define MFMA16(a, b, c) __builtin_amdgcn_mfma_f32_16x16x32_bf16(a, b, c, 0, 0, 0)

// ---------------- helpers ----------------

__device__ __forceinline__ unsigned mapf(float f) {
  unsigned u = __float_as_uint(f);
  return (u & 0x80000000u) ? ~u : (u | 0x80000000u);
}
__device__ __forceinline__ float unmapf(unsigned u) {
  return __uint_as_float((u & 0x80000000u) ? (u & 0x7FFFFFFFu) : ~u);
}
__device__ __forceinline__ ushort bf16_rne(float f) {
  unsigned u = __float_as_uint(f);
  u += 0x7FFFu + ((u >> 16) & 1u);
  return (ushort)(u >> 16);
}
__device__ __forceinline__ float bf16_tof(ushort h) {
  return __uint_as_float(((unsigned)h) << 16);
}

// ---------------- weight fragment prep ----------------
// wf layout (ushorts): region = (wi*2 + hl), wi = layer*2 + which.
// within region: frag f = ct*2+ks (8), lane (64), v (8): off = region*4096 + f*512 + lane*8 + v
// value = W[k][n], k = ks*32 + (lane>>4)*8 + v, n = ct*16 + (lane&15)

__global__ void wprep(const float* __restrict__ convW1, const float* __restrict__ convW2,
                      ushort* __restrict__ wf) {
  const int wi = blockIdx.x;  // 0..5
  const int layer = wi >> 1, which = wi & 1;
  const float* W = (which ? convW2 : convW1) + layer * 4096;
  const int t = threadIdx.x;  // 0..511
  const int f = t >> 6, lane = t & 63;
  const int ct = f >> 1, ks = f & 1;
  const int n = ct * 16 + (lane & 15);
  const int k0 = ks * 32 + ((lane >> 4) << 3);
  ushort hi[8], lo[8];
#pragma unroll
  for (int v = 0; v < 8; ++v) {
    float w = W[(k0 + v) * 64 + n];
    ushort h = bf16_rne(w);
    hi[v] = h;
    lo[v] = bf16_rne(w - bf16_tof(h));
  }
  *(uint4*)(wf + ((wi * 2 + 0) * 8 + f) * 512 + lane * 8) = *(uint4*)hi;
  *(uint4*)(wf + ((wi * 2 + 1) * 8 + f) * 512 + lane * 8) = *(uint4*)lo;
}

// ---------------- CSR build ----------------

__global__ void hist_kernel(const int* __restrict__ dst, int* __restrict__ deg) {
  int e = blockIdx.x * 256 + threadIdx.x;
  if (e < N_EDGES) atomicAdd(&deg[dst[e]], 1);
}

__global__ void scan_blocks(const int* __restrict__ deg, int* __restrict__ bsum) {
  __shared__ int sd[SCAN_B];
  int i = blockIdx.x * SCAN_B + threadIdx.x;
  sd[threadIdx.x] = (i < N_NODES) ? deg[i] : 0;
  __syncthreads();
  for (int off = SCAN_B / 2; off > 0; off >>= 1) {
    if (threadIdx.x < off) sd[threadIdx.x] += sd[threadIdx.x + off];
    __syncthreads();
  }
  if (threadIdx.x == 0) bsum[blockIdx.x] = sd[0];
}

__global__ void scan_mid(int* __restrict__ bsum) {
  __shared__ int s[256];
  int t = threadIdx.x;
  if (t < NB_SCAN) s[t] = bsum[t];
  __syncthreads();
  if (t == 0) {
    int run = 0;
    for (int i = 0; i < NB_SCAN; ++i) { int v = s[i]; s[i] = run; run += v; }
  }
  __syncthreads();
  if (t < NB_SCAN) bsum[t] = s[t];
}

__global__ void scan_final(const int* __restrict__ deg, const int* __restrict__ bsum,
                           int* __restrict__ rs, int* __restrict__ cur) {
  __shared__ int sd[SCAN_B];
  int i = blockIdx.x * SCAN_B + threadIdx.x;
  int v = (i < N_NODES) ? deg[i] : 0;
  sd[threadIdx.x] = v;
  __syncthreads();
  for (int off = 1; off < SCAN_B; off <<= 1) {
    int add = (threadIdx.x >= off) ? sd[threadIdx.x - off] : 0;
    __syncthreads();
    sd[threadIdx.x] += add;
    __syncthreads();
  }
  if (i < N_NODES) {
    int ex = bsum[blockIdx.x] + sd[threadIdx.x] - v;
    rs[i] = ex;
    cur[i] = ex;
  }
  if (i == 0) rs[N_NODES] = N_EDGES;
}

__global__ void fill_csr(const int* __restrict__ src, const int* __restrict__ dst,
                         int* __restrict__ cur, int* __restrict__ csr) {
  int e = blockIdx.x * 256 + threadIdx.x;
  if (e >= N_EDGES) return;
  int p = atomicAdd(&cur[dst[e]], 1);
  csr[p] = src[e];
}

// ---------------- GIN aggregation (f32 gather): acc[n] = h[n] + sum h[csr[e]] ----------------

__global__ __launch_bounds__(256) void agg_f32(
    const float* __restrict__ hin, const int* __restrict__ csr,
    const int* __restrict__ rs, float* __restrict__ acc) {
  const int t = threadIdx.x;
  const int hw = t >> 5, hl = t & 31;
  const int node = blockIdx.x * 8 + hw;
  const float2* __restrict__ H = (const float2*)hin;
  float2 a = H[node * 32 + hl];
  int e = rs[node];
  const int e1 = rs[node + 1];
  for (; e + 4 <= e1; e += 4) {
    int s0 = csr[e], s1 = csr[e + 1], s2 = csr[e + 2], s3 = csr[e + 3];
    float2 v0 = H[s0 * 32 + hl];
    float2 v1 = H[s1 * 32 + hl];
    float2 v2 = H[s2 * 32 + hl];
    float2 v3 = H[s3 * 32 + hl];
    a.x += v0.x + v1.x; a.y += v0.y + v1.y;
    a.x += v2.x + v3.x; a.y += v2.y + v3.y;
  }
  for (; e < e1; ++e) {
    float2 v = H[csr[e] * 32 + hl];
    a.x += v.x; a.y += v.y;
  }
  ((float2*)acc)[node * 32 + hl] = a;
}

// ---------------- MFMA MLP: A = relu(A@W1+b1)@W2+b2 (in-place; FINAL -> pool) ----------------
// One 16-row tile per wave. hi/lo bf16 split for ~f32 accuracy (3 MFMA per product).
// A-frag: lane holds row m=lane&15, k = (lane>>4)*8 + v. C/D: col=lane&15, row=(lane>>4)*4+reg.

template <int FINAL>
__global__ __launch_bounds__(256) void mlp_mfma(
    float* __restrict__ A,
    const ushort* __restrict__ wfL,  // W1hi@0, W1lo@4096, W2hi@8192, W2lo@12288
    const float* __restrict__ b1, const float* __restrict__ b2,
    const int* __restrict__ batch, unsigned* __restrict__ gU) {
  __shared__ char ldsraw[4][5504];
  const int t = threadIdx.x;
  const int w = t >> 6, lane = t & 63;
  const int tile = blockIdx.x * 4 + w;
  if (tile >= NT) return;
  const int m = lane & 15, g = lane >> 4;
  char* lds = ldsraw[w];

  // ---- load A row-fragments (f32) and split to bf16 hi/lo ----
  const float* Ar = A + (size_t)(tile * 16 + m) * 64;
  bf16x8 aH[2], aL[2];
#pragma unroll
  for (int ks = 0; ks < 2; ++ks) {
    float4 f0 = ((const float4*)Ar)[(ks * 32 + g * 8) >> 2];
    float4 f1 = ((const float4*)Ar)[((ks * 32 + g * 8) >> 2) + 1];
    float v[8] = {f0.x, f0.y, f0.z, f0.w, f1.x, f1.y, f1.z, f1.w};
#pragma unroll
    for (int e = 0; e < 8; ++e) {
      ushort h = bf16_rne(v[e]);
      aH[ks][e] = (short)h;
      aL[ks][e] = (short)bf16_rne(v[e] - bf16_tof(h));
    }
  }

  // ---- W1 fragments ----
  bf16x8 w1h[8], w1l[8];
#pragma unroll
  for (int f = 0; f < 8; ++f) {
    w1h[f] = *(const bf16x8*)(wfL + f * 512 + lane * 8);
    w1l[f] = *(const bf16x8*)(wfL + 4096 + f * 512 + lane * 8);
  }

  // ---- GEMM1: acc1 = A@W1 (hi/lo 3-product) ----
  f32x4 acc1[4];
#pragma unroll
  for (int ct = 0; ct < 4; ++ct) {
    f32x4 c = {0.f, 0.f, 0.f, 0.f};
    c = MFMA16(aH[0], w1h[ct * 2 + 0], c);
    c = MFMA16(aH[1], w1h[ct * 2 + 1], c);
    c = MFMA16(aL[0], w1h[ct * 2 + 0], c);
    c = MFMA16(aL[1], w1h[ct * 2 + 1], c);
    c = MFMA16(aH[0], w1l[ct * 2 + 0], c);
    c = MFMA16(aH[1], w1l[ct * 2 + 1], c);
    acc1[ct] = c;
  }

  // ---- bias + relu + split -> LDS transpose (C/D layout -> A-frag layout) ----
  ushort* Hhi = (ushort*)lds;            // [16][80]
  ushort* Hlo = (ushort*)(lds + 2560);   // [16][80]
#pragma unroll
  for (int ct = 0; ct < 4; ++ct) {
    float bias = b1[ct * 16 + m];
#pragma unroll
    for (int j = 0; j < 4; ++j) {
      float hv = fmaxf(acc1[ct][j] + bias, 0.f);
      ushort hh = bf16_rne(hv);
      int idx = (g * 4 + j) * 80 + ct * 16 + m;
      Hhi[idx] = hh;
      Hlo[idx] = bf16_rne(hv - bf16_tof(hh));
    }
  }

  bf16x8 hH[2], hL[2];
#pragma unroll
  for (int ks = 0; ks < 2; ++ks) {
    hH[ks] = *(const bf16x8*)(Hhi + m * 80 + ks * 32 + g * 8);
    hL[ks] = *(const bf16x8*)(Hlo + m * 80 + ks * 32 + g * 8);
  }

  // ---- W2 fragments + GEMM2 ----
  bf16x8 w2h[8], w2l[8];
#pragma unroll
  for (int f = 0; f < 8; ++f) {
    w2h[f] = *(const bf16x8*)(wfL + 8192 + f * 512 + lane * 8);
    w2l[f] = *(const bf16x8*)(wfL + 12288 + f * 512 + lane * 8);
  }
  f32x4 acc2[4];
#pragma unroll
  for (int ct = 0; ct < 4; ++ct) {
    f32x4 c = {0.f, 0.f, 0.f, 0.f};
    c = MFMA16(hH[0], w2h[ct * 2 + 0], c);
    c = MFMA16(hH[1], w2h[ct * 2 + 1], c);
    c = MFMA16(hL[0], w2h[ct * 2 + 0], c);
    c = MFMA16(hL[1], w2h[ct * 2 + 1], c);
    c = MFMA16(hH[0], w2l[ct * 2 + 0], c);
    c = MFMA16(hH[1], w2l[ct * 2 + 1], c);
    acc2[ct] = c;
  }

  if (FINAL) {
    int b4[4];
#pragma unroll
    for (int j = 0; j < 4; ++j) b4[j] = batch[tile * 16 + g * 4 + j];
#pragma unroll
    for (int ct = 0; ct < 4; ++ct) {
      float bias = b2[ct * 16 + m];
#pragma unroll
      for (int j = 0; j < 4; ++j) {
        float v = acc2[ct][j] + bias;
        atomicMax(&gU[b4[j] * 64 + ct * 16 + m], mapf(v));
      }
    }
  } else {
    // transpose out through LDS (reuse buffer) for coalesced f32 row stores
    float* O = (float*)lds;  // [16][84]
#pragma unroll
    for (int ct = 0; ct < 4; ++ct) {
      float bias = b2[ct * 16 + m];
#pragma unroll
      for (int j = 0; j < 4; ++j)
        O[(g * 4 + j) * 84 + ct * 16 + m] = acc2[ct][j] + bias;
    }
    float* Aw = A + (size_t)(tile * 16 + m) * 64;
#pragma unroll
    for (int q = 0; q < 4; ++q) {
      float4 vv = *(const float4*)(O + m * 84 + g * 16 + q * 4);
      ((float4*)Aw)[g * 4 + q] = vv;
    }
  }
}

// ---------------- pooling init + head ----------------

__global__ void init_g(unsigned* __restrict__ gU) {
  int i = blockIdx.x * blockDim.x + threadIdx.x;
  if (i < N_GRAPHS * D) gU[i] = 0x007FFFFFu;  // mapf(-inf)
}

__global__ void head_kernel(const unsigned* __restrict__ gU,
                            const float* __restrict__ fcW1, const float* __restrict__ fcb1,
                            const float* __restrict__ fcW2, const float* __restrict__ fcb2,
                            float* __restrict__ out) {
  __shared__ float gbuf[64];
  __shared__ float hid[64];
  __shared__ float logit[N_CLASSES];
  __shared__ float red[2];
  const int gi = blockIdx.x;
  const int t = threadIdx.x;

  gbuf[t] = unmapf(gU[gi * D + t]);
  __syncthreads();

  float a = fcb1[t];
#pragma unroll
  for (int k = 0; k < 64; ++k) a = fmaf(gbuf[k], fcW1[k * 64 + t], a);
  hid[t] = fmaxf(a, 0.0f);
  __syncthreads();

  if (t < N_CLASSES) {
    float l = fcb2[t];
#pragma unroll
    for (int k = 0; k < 64; ++k) l = fmaf(hid[k], fcW2[k * N_CLASSES + t], l);
    logit[t] = l;
  }
  __syncthreads();

  if (t == 0) {
    float mx = logit[0];
    for (int i = 1; i < N_CLASSES; ++i) mx = fmaxf(mx, logit[i]);
    float s = 0.0f;
    for (int i = 0; i < N_CLASSES; ++i) s += expf(logit[i] - mx);
    red[0] = mx;
    red[1] = logf(s);
  }
  __syncthreads();

  if (t < N_CLASSES) out[gi * N_CLASSES + t] = logit[t] - red[0] - red[1];
}

// ---------------- launch ----------------

extern "C" void kernel_launch(void* const* d_in, const int* in_sizes, int n_in,
                              void* d_out, int out_size, void* d_ws, size_t ws_size,
                              hipStream_t stream) {
  const float* x      = (const float*)d_in[0];
  const float* convW1 = (const float*)d_in[1];
  const float* convb1 = (const float*)d_in[2];
  const float* convW2 = (const float*)d_in[3];
  const float* convb2 = (const float*)d_in[4];
  const float* fcW1   = (const float*)d_in[5];
  const float* fcb1   = (const float*)d_in[6];
  const float* fcW2   = (const float*)d_in[7];
  const float* fcb2   = (const float*)d_in[8];
  const int*   edge   = (const int*)d_in[9];
  const int*   batch  = (const int*)d_in[10];
  float* out = (float*)d_out;

  const int* src = edge;
  const int* dst = edge + N_EDGES;

  // workspace layout (~29.2 MB)
  float* accA = (float*)d_ws;                              // 12.8 MB
  float* accB = accA + (size_t)N_NODES * 64;               // 12.8 MB
  unsigned* gU = (unsigned*)(accB + (size_t)N_NODES * 64); // 131 KB
  int* rs  = (int*)(gU + N_GRAPHS * D);                    // 200 KB
  int* csr = rs + N_NODES + 1;                             // 3.2 MB
  ushort* wf = (ushort*)(csr + N_EDGES);                   // 96 KB
  // deg/cur/bsum overlap accA (dead before accA is first written)
  int* deg  = (int*)accA;
  int* cur  = deg + N_NODES;
  int* bsum = cur + N_NODES;

  // ---- prep: W fragments + pool init ----
  wprep<<<6, 512, 0, stream>>>(convW1, convW2, wf);
  init_g<<<(N_GRAPHS * D + 255) / 256, 256, 0, stream>>>(gU);

  // ---- CSR build (dst-indexed) ----
  hipMemsetAsync(deg, 0, N_NODES * sizeof(int), stream);
  hist_kernel<<<N_EDGES / 256, 256, 0, stream>>>(dst, deg);
  scan_blocks<<<NB_SCAN, SCAN_B, 0, stream>>>(deg, bsum);
  scan_mid<<<1, 256, 0, stream>>>(bsum);
  scan_final<<<NB_SCAN, SCAN_B, 0, stream>>>(deg, bsum, rs, cur);
  fill_csr<<<N_EDGES / 256, 256, 0, stream>>>(src, dst, cur, csr);

  // ---- 3 GIN layers ----
  const int AGG_B = N_NODES / 8;       // 6250
  const int MLP_B = (NT + 3) / 4;      // 782
  agg_f32<<<AGG_B, 256, 0, stream>>>(x, csr, rs, accA);
  mlp_mfma<0><<<MLP_B, 256, 0, stream>>>(accA, wf, convb1, convb2, batch, gU);
  agg_f32<<<AGG_B, 256, 0, stream>>>(accA, csr, rs, accB);
  mlp_mfma<0><<<MLP_B, 256, 0, stream>>>(accB, wf + 16384, convb1 + 64, convb2 + 64,
                                         batch, gU);
  agg_f32<<<AGG_B, 256, 0, stream>>>(accB, csr, rs, accA);
  mlp_mfma<1><<<MLP_B, 256, 0, stream>>>(accA, wf + 32768, convb1 + 128, convb2 + 128,
                                         batch, gU);

  // ---- FC head + log_softmax ----
  head_kernel<<<N_GRAPHS, 64, 0, stream>>>(gU, fcW1, fcb1, fcW2, fcb2, out);
}

// Round 6
// 267.959 us; speedup vs baseline: 1.5289x; 1.0376x over previous
//
#include <hip/hip_runtime.h>
#include <math.h>

#define N_NODES 50000
#define N_EDGES 800000
#define D 64
#define N_GRAPHS 512
#define N_CLASSES 10
#define NT 3125  // 16-row tiles

#define SCAN_B 512
#define NB_SCAN ((N_NODES + SCAN_B - 1) / SCAN_B)  // 98

typedef __attribute__((ext_vector_type(8))) short bf16x8;
typedef __attribute__((ext_vector_type(4))) float f32x4;

#define MFMA16(a, b, c) __builtin_amdgcn_mfma_f32_16x16x32_bf16(a, b, c, 0, 0, 0)

// ---------------- helpers ----------------

__device__ __forceinline__ unsigned mapf(float f) {
  unsigned u = __float_as_uint(f);
  return (u & 0x80000000u) ? ~u : (u | 0x80000000u);
}
__device__ __forceinline__ float unmapf(unsigned u) {
  return __uint_as_float((u & 0x80000000u) ? (u & 0x7FFFFFFFu) : ~u);
}
__device__ __forceinline__ ushort bf16_rne(float f) {
  unsigned u = __float_as_uint(f);
  u += 0x7FFFu + ((u >> 16) & 1u);
  return (ushort)(u >> 16);
}
__device__ __forceinline__ float bf16_tof(ushort h) {
  return __uint_as_float(((unsigned)h) << 16);
}

__device__ __forceinline__ void split8(float4 p0, float4 p1, bf16x8& H, bf16x8& L) {
  ushort h;
  h = bf16_rne(p0.x); H[0] = (short)h; L[0] = (short)bf16_rne(p0.x - bf16_tof(h));
  h = bf16_rne(p0.y); H[1] = (short)h; L[1] = (short)bf16_rne(p0.y - bf16_tof(h));
  h = bf16_rne(p0.z); H[2] = (short)h; L[2] = (short)bf16_rne(p0.z - bf16_tof(h));
  h = bf16_rne(p0.w); H[3] = (short)h; L[3] = (short)bf16_rne(p0.w - bf16_tof(h));
  h = bf16_rne(p1.x); H[4] = (short)h; L[4] = (short)bf16_rne(p1.x - bf16_tof(h));
  h = bf16_rne(p1.y); H[5] = (short)h; L[5] = (short)bf16_rne(p1.y - bf16_tof(h));
  h = bf16_rne(p1.z); H[6] = (short)h; L[6] = (short)bf16_rne(p1.z - bf16_tof(h));
  h = bf16_rne(p1.w); H[7] = (short)h; L[7] = (short)bf16_rne(p1.w - bf16_tof(h));
}

// ---------------- weight fragment prep ----------------
// wf layout (ushorts): per layer 16384 ushorts (32KB): W1hi@0, W1lo@4096, W2hi@8192, W2lo@12288.
// within region: frag f (8), lane (64), v (8): off = f*512 + lane*8 + v
// value = W[k][n], k = (f&1)*32 + (lane>>4)*8 + v, n = (f>>1)*16 + (lane&15)

__global__ void wprep(const float* __restrict__ convW1, const float* __restrict__ convW2,
                      ushort* __restrict__ wf) {
  const int wi = blockIdx.x;  // 0..5 = layer*2 + which
  const int layer = wi >> 1, which = wi & 1;
  const float* W = (which ? convW2 : convW1) + layer * 4096;
  const int t = threadIdx.x;  // 0..511
  const int f = t >> 6, lane = t & 63;
  const int ct = f >> 1, ks = f & 1;
  const int n = ct * 16 + (lane & 15);
  const int k0 = ks * 32 + ((lane >> 4) << 3);
  ushort hi[8], lo[8];
#pragma unroll
  for (int v = 0; v < 8; ++v) {
    float w = W[(k0 + v) * 64 + n];
    ushort h = bf16_rne(w);
    hi[v] = h;
    lo[v] = bf16_rne(w - bf16_tof(h));
  }
  ushort* base = wf + layer * 16384 + which * 8192;
  *(uint4*)(base + f * 512 + lane * 8) = *(uint4*)hi;          // hi region
  *(uint4*)(base + 4096 + f * 512 + lane * 8) = *(uint4*)lo;   // lo region
}

// ---------------- CSR build ----------------

__global__ void hist_kernel(const int* __restrict__ dst, int* __restrict__ deg) {
  int e = blockIdx.x * 256 + threadIdx.x;
  if (e < N_EDGES) atomicAdd(&deg[dst[e]], 1);
}

__global__ void scan_blocks(const int* __restrict__ deg, int* __restrict__ bsum) {
  __shared__ int sd[SCAN_B];
  int i = blockIdx.x * SCAN_B + threadIdx.x;
  sd[threadIdx.x] = (i < N_NODES) ? deg[i] : 0;
  __syncthreads();
  for (int off = SCAN_B / 2; off > 0; off >>= 1) {
    if (threadIdx.x < off) sd[threadIdx.x] += sd[threadIdx.x + off];
    __syncthreads();
  }
  if (threadIdx.x == 0) bsum[blockIdx.x] = sd[0];
}

__global__ void scan_mid(int* __restrict__ bsum) {
  __shared__ int s[256];
  int t = threadIdx.x;
  if (t < NB_SCAN) s[t] = bsum[t];
  __syncthreads();
  if (t == 0) {
    int run = 0;
    for (int i = 0; i < NB_SCAN; ++i) { int v = s[i]; s[i] = run; run += v; }
  }
  __syncthreads();
  if (t < NB_SCAN) bsum[t] = s[t];
}

__global__ void scan_final(const int* __restrict__ deg, const int* __restrict__ bsum,
                           int* __restrict__ rs, int* __restrict__ cur) {
  __shared__ int sd[SCAN_B];
  int i = blockIdx.x * SCAN_B + threadIdx.x;
  int v = (i < N_NODES) ? deg[i] : 0;
  sd[threadIdx.x] = v;
  __syncthreads();
  for (int off = 1; off < SCAN_B; off <<= 1) {
    int add = (threadIdx.x >= off) ? sd[threadIdx.x - off] : 0;
    __syncthreads();
    sd[threadIdx.x] += add;
    __syncthreads();
  }
  if (i < N_NODES) {
    int ex = bsum[blockIdx.x] + sd[threadIdx.x] - v;
    rs[i] = ex;
    cur[i] = ex;
  }
  if (i == 0) rs[N_NODES] = N_EDGES;
}

__global__ void fill_csr(const int* __restrict__ src, const int* __restrict__ dst,
                         int* __restrict__ cur, int* __restrict__ csr) {
  int e = blockIdx.x * 256 + threadIdx.x;
  if (e >= N_EDGES) return;
  int p = atomicAdd(&cur[dst[e]], 1);
  csr[p] = src[e];
}

// ---------------- GIN aggregation (f32 gather): acc[n] = h[n] + sum h[csr[e]] ----------------

__global__ __launch_bounds__(256) void agg_f32(
    const float* __restrict__ hin, const int* __restrict__ csr,
    const int* __restrict__ rs, float* __restrict__ acc) {
  const int t = threadIdx.x;
  const int hw = t >> 5, hl = t & 31;
  const int node = blockIdx.x * 8 + hw;
  const float2* __restrict__ H = (const float2*)hin;
  float2 a = H[node * 32 + hl];
  int e = rs[node];
  const int e1 = rs[node + 1];
  for (; e + 4 <= e1; e += 4) {
    int s0 = csr[e], s1 = csr[e + 1], s2 = csr[e + 2], s3 = csr[e + 3];
    float2 v0 = H[s0 * 32 + hl];
    float2 v1 = H[s1 * 32 + hl];
    float2 v2 = H[s2 * 32 + hl];
    float2 v3 = H[s3 * 32 + hl];
    a.x += v0.x + v1.x; a.y += v0.y + v1.y;
    a.x += v2.x + v3.x; a.y += v2.y + v3.y;
  }
  for (; e < e1; ++e) {
    float2 v = H[csr[e] * 32 + hl];
    a.x += v.x; a.y += v.y;
  }
  ((float2*)acc)[node * 32 + hl] = a;
}

// ---------------- MFMA MLP: A = relu(A@W1+b1)@W2+b2 (in-place; FINAL -> pool) ----------------
// Weights in LDS (32KB/block, ds_read_b128 per MFMA operand). A/H fragments in
// named registers (no arrays -> no scratch). hi/lo bf16 split, 3 MFMA/product.
// A-frag: lane(row m=lane&15), k=(ks*32)+(lane>>4)*8+v. C/D: col=lane&15, row=(lane>>4)*4+j.

template <int FINAL>
__global__ __launch_bounds__(256) void mlp_mfma(
    float* __restrict__ A,
    const ushort* __restrict__ wfL,  // layer base: W1hi@0 W1lo@8KB W2hi@16KB W2lo@24KB
    const float* __restrict__ b1, const float* __restrict__ b2,
    const int* __restrict__ batch, unsigned* __restrict__ gU) {
  __shared__ char lds[32768 + 4 * 2560];
  const int t = threadIdx.x;
  const int w = t >> 6, lane = t & 63;

  // ---- stage 32KB of weight fragments ----
  {
    const uint4* s = (const uint4*)wfL;
    uint4* d = (uint4*)lds;
#pragma unroll
    for (int i = 0; i < 8; ++i) d[t + 256 * i] = s[t + 256 * i];
  }
  __syncthreads();

  const int tile = blockIdx.x * 4 + w;
  if (tile >= NT) return;
  const int m = lane & 15, g = lane >> 4;
  const char* wb = lds + lane * 16;           // per-lane weight base
  ushort* tb16 = (ushort*)(lds + 32768 + w * 2560);  // per-wave [16][80] transpose buf

  // ---- load A row (f32) and split hi/lo ----
  const float* Ar = A + (size_t)(tile * 16 + m) * 64;
  bf16x8 aH0, aH1, aL0, aL1;
  {
    float4 p0 = *(const float4*)(Ar + g * 8);
    float4 p1 = *(const float4*)(Ar + g * 8 + 4);
    float4 p2 = *(const float4*)(Ar + 32 + g * 8);
    float4 p3 = *(const float4*)(Ar + 32 + g * 8 + 4);
    split8(p0, p1, aH0, aL0);
    split8(p2, p3, aH1, aL1);
  }

#define LDW(off) (*(const bf16x8*)(wb + (off)))

  // ---- GEMM1: c1 = A@W1 (hi*hi + lo*hi + hi*lo) ----
  f32x4 c1_0 = {0.f, 0.f, 0.f, 0.f}, c1_1 = c1_0, c1_2 = c1_0, c1_3 = c1_0;
#define G1(ct, cc)                                   \
  cc = MFMA16(aH0, LDW((2 * ct + 0) * 1024), cc);    \
  cc = MFMA16(aH1, LDW((2 * ct + 1) * 1024), cc);    \
  cc = MFMA16(aL0, LDW((2 * ct + 0) * 1024), cc);    \
  cc = MFMA16(aL1, LDW((2 * ct + 1) * 1024), cc);    \
  cc = MFMA16(aH0, LDW(8192 + (2 * ct + 0) * 1024), cc); \
  cc = MFMA16(aH1, LDW(8192 + (2 * ct + 1) * 1024), cc);
  G1(0, c1_0) G1(1, c1_1) G1(2, c1_2) G1(3, c1_3)
#undef G1

  // ---- bias + relu (keep f32 in c1_*) ----
  {
    float bv0 = b1[m], bv1 = b1[16 + m], bv2 = b1[32 + m], bv3 = b1[48 + m];
#define BR(cc, bv)                     \
    cc[0] = fmaxf(cc[0] + bv, 0.f);    \
    cc[1] = fmaxf(cc[1] + bv, 0.f);    \
    cc[2] = fmaxf(cc[2] + bv, 0.f);    \
    cc[3] = fmaxf(cc[3] + bv, 0.f);
    BR(c1_0, bv0) BR(c1_1, bv1) BR(c1_2, bv2) BR(c1_3, bv3)
#undef BR
  }

  // ---- transpose H (C/D layout -> A-frag layout) via per-wave LDS, hi then lo ----
#define WRH(cc, ct)                                                    \
  tb16[(g * 4 + 0) * 80 + ct * 16 + m] = bf16_rne(cc[0]);              \
  tb16[(g * 4 + 1) * 80 + ct * 16 + m] = bf16_rne(cc[1]);              \
  tb16[(g * 4 + 2) * 80 + ct * 16 + m] = bf16_rne(cc[2]);              \
  tb16[(g * 4 + 3) * 80 + ct * 16 + m] = bf16_rne(cc[3]);
  WRH(c1_0, 0) WRH(c1_1, 1) WRH(c1_2, 2) WRH(c1_3, 3)
#undef WRH
  bf16x8 hH0 = *(const bf16x8*)(tb16 + m * 80 + g * 8);
  bf16x8 hH1 = *(const bf16x8*)(tb16 + m * 80 + 32 + g * 8);

#define WRL(cc, ct)                                                                  \
  { float hv; ushort hh;                                                             \
    hv = cc[0]; hh = bf16_rne(hv);                                                   \
    tb16[(g * 4 + 0) * 80 + ct * 16 + m] = bf16_rne(hv - bf16_tof(hh));              \
    hv = cc[1]; hh = bf16_rne(hv);                                                   \
    tb16[(g * 4 + 1) * 80 + ct * 16 + m] = bf16_rne(hv - bf16_tof(hh));              \
    hv = cc[2]; hh = bf16_rne(hv);                                                   \
    tb16[(g * 4 + 2) * 80 + ct * 16 + m] = bf16_rne(hv - bf16_tof(hh));              \
    hv = cc[3]; hh = bf16_rne(hv);                                                   \
    tb16[(g * 4 + 3) * 80 + ct * 16 + m] = bf16_rne(hv - bf16_tof(hh)); }
  WRL(c1_0, 0) WRL(c1_1, 1) WRL(c1_2, 2) WRL(c1_3, 3)
#undef WRL
  bf16x8 hL0 = *(const bf16x8*)(tb16 + m * 80 + g * 8);
  bf16x8 hL1 = *(const bf16x8*)(tb16 + m * 80 + 32 + g * 8);

  // ---- GEMM2: c2 = H@W2 ----
  f32x4 c2_0 = {0.f, 0.f, 0.f, 0.f}, c2_1 = c2_0, c2_2 = c2_0, c2_3 = c2_0;
#define G2(ct, cc)                                          \
  cc = MFMA16(hH0, LDW(16384 + (2 * ct + 0) * 1024), cc);   \
  cc = MFMA16(hH1, LDW(16384 + (2 * ct + 1) * 1024), cc);   \
  cc = MFMA16(hL0, LDW(16384 + (2 * ct + 0) * 1024), cc);   \
  cc = MFMA16(hL1, LDW(16384 + (2 * ct + 1) * 1024), cc);   \
  cc = MFMA16(hH0, LDW(24576 + (2 * ct + 0) * 1024), cc);   \
  cc = MFMA16(hH1, LDW(24576 + (2 * ct + 1) * 1024), cc);
  G2(0, c2_0) G2(1, c2_1) G2(2, c2_2) G2(3, c2_3)
#undef G2
#undef LDW

  float bv0 = b2[m], bv1 = b2[16 + m], bv2 = b2[32 + m], bv3 = b2[48 + m];
  if (FINAL) {
    int b40 = batch[tile * 16 + g * 4 + 0];
    int b41 = batch[tile * 16 + g * 4 + 1];
    int b42 = batch[tile * 16 + g * 4 + 2];
    int b43 = batch[tile * 16 + g * 4 + 3];
#define PM(cc, ct, bv)                                          \
    atomicMax(&gU[b40 * 64 + ct * 16 + m], mapf(cc[0] + bv));   \
    atomicMax(&gU[b41 * 64 + ct * 16 + m], mapf(cc[1] + bv));   \
    atomicMax(&gU[b42 * 64 + ct * 16 + m], mapf(cc[2] + bv));   \
    atomicMax(&gU[b43 * 64 + ct * 16 + m], mapf(cc[3] + bv));
    PM(c2_0, 0, bv0) PM(c2_1, 1, bv1) PM(c2_2, 2, bv2) PM(c2_3, 3, bv3)
#undef PM
  } else {
    float* Aw = A + (size_t)tile * 1024;
#define ST(cc, ct, bv)                                         \
    Aw[(g * 4 + 0) * 64 + ct * 16 + m] = cc[0] + bv;           \
    Aw[(g * 4 + 1) * 64 + ct * 16 + m] = cc[1] + bv;           \
    Aw[(g * 4 + 2) * 64 + ct * 16 + m] = cc[2] + bv;           \
    Aw[(g * 4 + 3) * 64 + ct * 16 + m] = cc[3] + bv;
    ST(c2_0, 0, bv0) ST(c2_1, 1, bv1) ST(c2_2, 2, bv2) ST(c2_3, 3, bv3)
#undef ST
  }
}

// ---------------- pooling init + head ----------------

__global__ void init_g(unsigned* __restrict__ gU) {
  int i = blockIdx.x * blockDim.x + threadIdx.x;
  if (i < N_GRAPHS * D) gU[i] = 0x007FFFFFu;  // mapf(-inf)
}

__global__ void head_kernel(const unsigned* __restrict__ gU,
                            const float* __restrict__ fcW1, const float* __restrict__ fcb1,
                            const float* __restrict__ fcW2, const float* __restrict__ fcb2,
                            float* __restrict__ out) {
  __shared__ float gbuf[64];
  __shared__ float hid[64];
  __shared__ float logit[N_CLASSES];
  __shared__ float red[2];
  const int gi = blockIdx.x;
  const int t = threadIdx.x;

  gbuf[t] = unmapf(gU[gi * D + t]);
  __syncthreads();

  float a = fcb1[t];
#pragma unroll
  for (int k = 0; k < 64; ++k) a = fmaf(gbuf[k], fcW1[k * 64 + t], a);
  hid[t] = fmaxf(a, 0.0f);
  __syncthreads();

  if (t < N_CLASSES) {
    float l = fcb2[t];
#pragma unroll
    for (int k = 0; k < 64; ++k) l = fmaf(hid[k], fcW2[k * N_CLASSES + t], l);
    logit[t] = l;
  }
  __syncthreads();

  if (t == 0) {
    float mx = logit[0];
    for (int i = 1; i < N_CLASSES; ++i) mx = fmaxf(mx, logit[i]);
    float s = 0.0f;
    for (int i = 0; i < N_CLASSES; ++i) s += expf(logit[i] - mx);
    red[0] = mx;
    red[1] = logf(s);
  }
  __syncthreads();

  if (t < N_CLASSES) out[gi * N_CLASSES + t] = logit[t] - red[0] - red[1];
}

// ---------------- launch ----------------

extern "C" void kernel_launch(void* const* d_in, const int* in_sizes, int n_in,
                              void* d_out, int out_size, void* d_ws, size_t ws_size,
                              hipStream_t stream) {
  const float* x      = (const float*)d_in[0];
  const float* convW1 = (const float*)d_in[1];
  const float* convb1 = (const float*)d_in[2];
  const float* convW2 = (const float*)d_in[3];
  const float* convb2 = (const float*)d_in[4];
  const float* fcW1   = (const float*)d_in[5];
  const float* fcb1   = (const float*)d_in[6];
  const float* fcW2   = (const float*)d_in[7];
  const float* fcb2   = (const float*)d_in[8];
  const int*   edge   = (const int*)d_in[9];
  const int*   batch  = (const int*)d_in[10];
  float* out = (float*)d_out;

  const int* src = edge;
  const int* dst = edge + N_EDGES;

  // workspace layout (~29.2 MB)
  float* accA = (float*)d_ws;                              // 12.8 MB
  float* accB = accA + (size_t)N_NODES * 64;               // 12.8 MB
  unsigned* gU = (unsigned*)(accB + (size_t)N_NODES * 64); // 131 KB
  int* rs  = (int*)(gU + N_GRAPHS * D);                    // 200 KB
  int* csr = rs + N_NODES + 1;                             // 3.2 MB
  ushort* wf = (ushort*)(csr + N_EDGES);                   // 96 KB
  // deg/cur/bsum overlap accA (dead before accA is first written)
  int* deg  = (int*)accA;
  int* cur  = deg + N_NODES;
  int* bsum = cur + N_NODES;

  // ---- prep: W fragments + pool init ----
  wprep<<<6, 512, 0, stream>>>(convW1, convW2, wf);
  init_g<<<(N_GRAPHS * D + 255) / 256, 256, 0, stream>>>(gU);

  // ---- CSR build (dst-indexed) ----
  hipMemsetAsync(deg, 0, N_NODES * sizeof(int), stream);
  hist_kernel<<<N_EDGES / 256, 256, 0, stream>>>(dst, deg);
  scan_blocks<<<NB_SCAN, SCAN_B, 0, stream>>>(deg, bsum);
  scan_mid<<<1, 256, 0, stream>>>(bsum);
  scan_final<<<NB_SCAN, SCAN_B, 0, stream>>>(deg, bsum, rs, cur);
  fill_csr<<<N_EDGES / 256, 256, 0, stream>>>(src, dst, cur, csr);

  // ---- 3 GIN layers ----
  const int AGG_B = N_NODES / 8;    // 6250
  const int MLP_B = (NT + 3) / 4;   // 782
  agg_f32<<<AGG_B, 256, 0, stream>>>(x, csr, rs, accA);
  mlp_mfma<0><<<MLP_B, 256, 0, stream>>>(accA, wf, convb1, convb2, batch, gU);
  agg_f32<<<AGG_B, 256, 0, stream>>>(accA, csr, rs, accB);
  mlp_mfma<0><<<MLP_B, 256, 0, stream>>>(accB, wf + 16384, convb1 + 64, convb2 + 64,
                                         batch, gU);
  agg_f32<<<AGG_B, 256, 0, stream>>>(accB, csr, rs, accA);
  mlp_mfma<1><<<MLP_B, 256, 0, stream>>>(accA, wf + 32768, convb1 + 128, convb2 + 128,
                                         batch, gU);

  // ---- FC head + log_softmax ----
  head_kernel<<<N_GRAPHS, 64, 0, stream>>>(gU, fcW1, fcb1, fcW2, fcb2, out);
}

// Round 7
// 242.637 us; speedup vs baseline: 1.6884x; 1.1044x over previous
//
#include <hip/hip_runtime.h>
#include <math.h>

#define N_NODES 50000
#define N_EDGES 800000
#define D 64
#define N_GRAPHS 512
#define N_CLASSES 10
#define NT 3125  // 16-row tiles

#define SCAN_B 512
#define NB_SCAN ((N_NODES + SCAN_B - 1) / SCAN_B)  // 98

typedef __attribute__((ext_vector_type(8))) short bf16x8;
typedef __attribute__((ext_vector_type(4))) float f32x4;

#define MFMA16(a, b, c) __builtin_amdgcn_mfma_f32_16x16x32_bf16(a, b, c, 0, 0, 0)

// ---------------- helpers ----------------

__device__ __forceinline__ unsigned mapf(float f) {
  unsigned u = __float_as_uint(f);
  return (u & 0x80000000u) ? ~u : (u | 0x80000000u);
}
__device__ __forceinline__ float unmapf(unsigned u) {
  return __uint_as_float((u & 0x80000000u) ? (u & 0x7FFFFFFFu) : ~u);
}
__device__ __forceinline__ ushort bf16_rne(float f) {
  unsigned u = __float_as_uint(f);
  u += 0x7FFFu + ((u >> 16) & 1u);
  return (ushort)(u >> 16);
}
__device__ __forceinline__ float bf16_tof(ushort h) {
  return __uint_as_float(((unsigned)h) << 16);
}
__device__ __forceinline__ unsigned pack2(float a, float b) {
  return (unsigned)bf16_rne(a) | ((unsigned)bf16_rne(b) << 16);
}
__device__ __forceinline__ float2 unpack2(unsigned v) {
  return make_float2(__uint_as_float(v << 16), __uint_as_float(v & 0xFFFF0000u));
}

// ---------------- x -> bf16 ----------------

__global__ void to_bf16(const float* __restrict__ in, unsigned* __restrict__ out) {
  int i = blockIdx.x * 256 + threadIdx.x;  // one float4 -> uint2 per thread
  float4 v = reinterpret_cast<const float4*>(in)[i];
  reinterpret_cast<uint2*>(out)[i] = make_uint2(pack2(v.x, v.y), pack2(v.z, v.w));
}

// ---------------- weight fragment prep (hi/lo split) ----------------
// wf layout (ushorts): per layer 16384: W1hi@0, W1lo@4096, W2hi@8192, W2lo@12288.
// within region: frag f (8), lane (64), v (8): off = f*512 + lane*8 + v
// value = W[k][n], k = (f&1)*32 + (lane>>4)*8 + v, n = (f>>1)*16 + (lane&15)

__global__ void wprep(const float* __restrict__ convW1, const float* __restrict__ convW2,
                      ushort* __restrict__ wf) {
  const int wi = blockIdx.x;  // 0..5 = layer*2 + which
  const int layer = wi >> 1, which = wi & 1;
  const float* W = (which ? convW2 : convW1) + layer * 4096;
  const int t = threadIdx.x;  // 0..511
  const int f = t >> 6, lane = t & 63;
  const int ct = f >> 1, ks = f & 1;
  const int n = ct * 16 + (lane & 15);
  const int k0 = ks * 32 + ((lane >> 4) << 3);
  ushort hi[8], lo[8];
#pragma unroll
  for (int v = 0; v < 8; ++v) {
    float w = W[(k0 + v) * 64 + n];
    ushort h = bf16_rne(w);
    hi[v] = h;
    lo[v] = bf16_rne(w - bf16_tof(h));
  }
  ushort* base = wf + layer * 16384 + which * 8192;
  *(uint4*)(base + f * 512 + lane * 8) = *(uint4*)hi;
  *(uint4*)(base + 4096 + f * 512 + lane * 8) = *(uint4*)lo;
}

// ---------------- CSR build ----------------

__global__ void hist_kernel(const int* __restrict__ dst, int* __restrict__ deg) {
  int e = blockIdx.x * 256 + threadIdx.x;
  if (e < N_EDGES) atomicAdd(&deg[dst[e]], 1);
}

__global__ void scan_blocks(const int* __restrict__ deg, int* __restrict__ bsum) {
  __shared__ int sd[SCAN_B];
  int i = blockIdx.x * SCAN_B + threadIdx.x;
  sd[threadIdx.x] = (i < N_NODES) ? deg[i] : 0;
  __syncthreads();
  for (int off = SCAN_B / 2; off > 0; off >>= 1) {
    if (threadIdx.x < off) sd[threadIdx.x] += sd[threadIdx.x + off];
    __syncthreads();
  }
  if (threadIdx.x == 0) bsum[blockIdx.x] = sd[0];
}

__global__ void scan_mid(int* __restrict__ bsum) {
  __shared__ int s[256];
  int t = threadIdx.x;
  if (t < NB_SCAN) s[t] = bsum[t];
  __syncthreads();
  if (t == 0) {
    int run = 0;
    for (int i = 0; i < NB_SCAN; ++i) { int v = s[i]; s[i] = run; run += v; }
  }
  __syncthreads();
  if (t < NB_SCAN) bsum[t] = s[t];
}

__global__ void scan_final(const int* __restrict__ deg, const int* __restrict__ bsum,
                           int* __restrict__ rs, int* __restrict__ cur) {
  __shared__ int sd[SCAN_B];
  int i = blockIdx.x * SCAN_B + threadIdx.x;
  int v = (i < N_NODES) ? deg[i] : 0;
  sd[threadIdx.x] = v;
  __syncthreads();
  for (int off = 1; off < SCAN_B; off <<= 1) {
    int add = (threadIdx.x >= off) ? sd[threadIdx.x - off] : 0;
    __syncthreads();
    sd[threadIdx.x] += add;
    __syncthreads();
  }
  if (i < N_NODES) {
    int ex = bsum[blockIdx.x] + sd[threadIdx.x] - v;
    rs[i] = ex;
    cur[i] = ex;
  }
  if (i == 0) rs[N_NODES] = N_EDGES;
}

__global__ void fill_csr(const int* __restrict__ src, const int* __restrict__ dst,
                         int* __restrict__ cur, int* __restrict__ csr) {
  int e = blockIdx.x * 256 + threadIdx.x;
  if (e >= N_EDGES) return;
  int p = atomicAdd(&cur[dst[e]], 1);
  csr[p] = src[e];
}

// ---------------- GIN aggregation: out[n] = bf16( h[n] + sum h[csr[e]] ) ----------------
// bf16 in, f32 accumulate, bf16 out. Half-wave (32 lanes) per node, 2 feats/lane.

__global__ __launch_bounds__(256) void agg_bf16(
    const unsigned* __restrict__ hin, const int* __restrict__ csr,
    const int* __restrict__ rs, unsigned* __restrict__ hout) {
  const int t = threadIdx.x;
  const int hw = t >> 5, hl = t & 31;
  const int node = blockIdx.x * 8 + hw;
  float2 a = unpack2(hin[node * 32 + hl]);  // self term
  int e = rs[node];
  const int e1 = rs[node + 1];
  for (; e + 4 <= e1; e += 4) {
    int s0 = csr[e], s1 = csr[e + 1], s2 = csr[e + 2], s3 = csr[e + 3];
    float2 v0 = unpack2(hin[s0 * 32 + hl]);
    float2 v1 = unpack2(hin[s1 * 32 + hl]);
    float2 v2 = unpack2(hin[s2 * 32 + hl]);
    float2 v3 = unpack2(hin[s3 * 32 + hl]);
    a.x += v0.x + v1.x; a.y += v0.y + v1.y;
    a.x += v2.x + v3.x; a.y += v2.y + v3.y;
  }
  for (; e < e1; ++e) {
    float2 v = unpack2(hin[csr[e] * 32 + hl]);
    a.x += v.x; a.y += v.y;
  }
  hout[node * 32 + hl] = pack2(a.x, a.y);
}

// ---------------- MFMA MLP (bf16): A = relu(A@W1+b1)@W2+b2, in-place ----------------
// A bf16 rows -> exact MFMA A-frags (no split). Weights hi/lo (2 MFMA/product).
// 32 MFMA/wave. One 16KB weight stage at a time. Per-wave LDS transpose [16][72].
// A-frag: lane row=lane&15, k=(ks*32)+(lane>>4)*8+v. C/D: col=lane&15, row=(lane>>4)*4+j.

template <int FINAL>
__global__ __launch_bounds__(256, 4) void mlp_bf16(
    unsigned* __restrict__ A,        // bf16 rows, in-place
    const ushort* __restrict__ wfL,  // layer base: W1hi@0 W1lo@8KB W2hi@16KB W2lo@24KB (bytes)
    const float* __restrict__ b1, const float* __restrict__ b2,
    const int* __restrict__ batch, unsigned* __restrict__ gU) {
  __shared__ ushort Wl[8192];        // 16KB: hi@0, lo@4096 (ushorts)
  __shared__ ushort tb[4][16 * 72];  // per-wave transpose, stride 72 ushorts (144B)
  const int t = threadIdx.x;
  const int w = t >> 6, lane = t & 63;
  const int tile = blockIdx.x * 4 + w;
  const bool act = (tile < NT);
  const int m = lane & 15, g = lane >> 4;
  ushort* tw = tb[w];

  // ---- stage W1 hi+lo (16KB) ----
  {
    const uint4* s = (const uint4*)wfL;
    uint4* d = (uint4*)Wl;
#pragma unroll
    for (int i = 0; i < 4; ++i) d[t + 256 * i] = s[t + 256 * i];
  }

  // ---- A fragments: exact bf16 loads (row = m, k = ks*32 + g*8 + v) ----
  bf16x8 a0 = {}, a1 = {};
  if (act) {
    const ushort* Ar = (const ushort*)A + (size_t)(tile * 16 + m) * 64;
    a0 = *(const bf16x8*)(Ar + g * 8);
    a1 = *(const bf16x8*)(Ar + 32 + g * 8);
  }
  __syncthreads();

  const char* wb = (const char*)Wl + lane * 16;
#define LDW(off) (*(const bf16x8*)(wb + (off)))

  f32x4 c0 = {0.f, 0.f, 0.f, 0.f}, c1 = c0, c2 = c0, c3 = c0;
  bf16x8 h0 = {}, h1 = {};
  if (act) {
    // ---- GEMM1: c = A@(W1hi + W1lo) ----
#define G1(ct, cc)                                     \
    cc = MFMA16(a0, LDW((2 * ct + 0) * 1024), cc);     \
    cc = MFMA16(a1, LDW((2 * ct + 1) * 1024), cc);     \
    cc = MFMA16(a0, LDW(8192 + (2 * ct + 0) * 1024), cc); \
    cc = MFMA16(a1, LDW(8192 + (2 * ct + 1) * 1024), cc);
    G1(0, c0) G1(1, c1) G1(2, c2) G1(3, c3)
#undef G1

    // ---- bias + relu -> bf16 transpose (C/D -> A-frag layout) ----
    float bv0 = b1[m], bv1 = b1[16 + m], bv2 = b1[32 + m], bv3 = b1[48 + m];
#define WRT(cc, ct, bv)                                               \
    tw[(g * 4 + 0) * 72 + ct * 16 + m] = bf16_rne(fmaxf(cc[0] + bv, 0.f)); \
    tw[(g * 4 + 1) * 72 + ct * 16 + m] = bf16_rne(fmaxf(cc[1] + bv, 0.f)); \
    tw[(g * 4 + 2) * 72 + ct * 16 + m] = bf16_rne(fmaxf(cc[2] + bv, 0.f)); \
    tw[(g * 4 + 3) * 72 + ct * 16 + m] = bf16_rne(fmaxf(cc[3] + bv, 0.f));
    WRT(c0, 0, bv0) WRT(c1, 1, bv1) WRT(c2, 2, bv2) WRT(c3, 3, bv3)
#undef WRT
    h0 = *(const bf16x8*)(tw + m * 72 + g * 8);
    h1 = *(const bf16x8*)(tw + m * 72 + 32 + g * 8);
  }
  __syncthreads();  // all GEMM1 weight reads done

  // ---- stage W2 hi+lo (16KB) ----
  {
    const uint4* s = (const uint4*)(wfL + 8192);
    uint4* d = (uint4*)Wl;
#pragma unroll
    for (int i = 0; i < 4; ++i) d[t + 256 * i] = s[t + 256 * i];
  }
  __syncthreads();

  if (act) {
    // ---- GEMM2: c = H@(W2hi + W2lo) ----
    c0 = (f32x4){0.f, 0.f, 0.f, 0.f}; c1 = c0; c2 = c0; c3 = c0;
#define G2(ct, cc)                                     \
    cc = MFMA16(h0, LDW((2 * ct + 0) * 1024), cc);     \
    cc = MFMA16(h1, LDW((2 * ct + 1) * 1024), cc);     \
    cc = MFMA16(h0, LDW(8192 + (2 * ct + 0) * 1024), cc); \
    cc = MFMA16(h1, LDW(8192 + (2 * ct + 1) * 1024), cc);
    G2(0, c0) G2(1, c1) G2(2, c2) G2(3, c3)
#undef G2
#undef LDW

    float bv0 = b2[m], bv1 = b2[16 + m], bv2 = b2[32 + m], bv3 = b2[48 + m];
    if (FINAL) {
      int b40 = batch[tile * 16 + g * 4 + 0];
      int b41 = batch[tile * 16 + g * 4 + 1];
      int b42 = batch[tile * 16 + g * 4 + 2];
      int b43 = batch[tile * 16 + g * 4 + 3];
#define PM(cc, ct, bv)                                          \
      atomicMax(&gU[b40 * 64 + ct * 16 + m], mapf(cc[0] + bv)); \
      atomicMax(&gU[b41 * 64 + ct * 16 + m], mapf(cc[1] + bv)); \
      atomicMax(&gU[b42 * 64 + ct * 16 + m], mapf(cc[2] + bv)); \
      atomicMax(&gU[b43 * 64 + ct * 16 + m], mapf(cc[3] + bv));
      PM(c0, 0, bv0) PM(c1, 1, bv1) PM(c2, 2, bv2) PM(c3, 3, bv3)
#undef PM
    } else {
      // out -> bf16 via per-wave LDS, then coalesced 16B stores
#define WRO(cc, ct, bv)                                    \
      tw[(g * 4 + 0) * 72 + ct * 16 + m] = bf16_rne(cc[0] + bv); \
      tw[(g * 4 + 1) * 72 + ct * 16 + m] = bf16_rne(cc[1] + bv); \
      tw[(g * 4 + 2) * 72 + ct * 16 + m] = bf16_rne(cc[2] + bv); \
      tw[(g * 4 + 3) * 72 + ct * 16 + m] = bf16_rne(cc[3] + bv);
      WRO(c0, 0, bv0) WRO(c1, 1, bv1) WRO(c2, 2, bv2) WRO(c3, 3, bv3)
#undef WRO
      // lane: row m, 16-ushort chunk g
      uint4 v0 = *(const uint4*)(tw + m * 72 + g * 16);
      uint4 v1 = *(const uint4*)(tw + m * 72 + g * 16 + 8);
      uint4* Aw = (uint4*)((ushort*)A + (size_t)(tile * 16 + m) * 64 + g * 16);
      Aw[0] = v0;
      Aw[1] = v1;
    }
  }
}

// ---------------- pooling init + head ----------------

__global__ void init_g(unsigned* __restrict__ gU) {
  int i = blockIdx.x * blockDim.x + threadIdx.x;
  if (i < N_GRAPHS * D) gU[i] = 0x007FFFFFu;  // mapf(-inf)
}

__global__ void head_kernel(const unsigned* __restrict__ gU,
                            const float* __restrict__ fcW1, const float* __restrict__ fcb1,
                            const float* __restrict__ fcW2, const float* __restrict__ fcb2,
                            float* __restrict__ out) {
  __shared__ float gbuf[64];
  __shared__ float hid[64];
  __shared__ float logit[N_CLASSES];
  __shared__ float red[2];
  const int gi = blockIdx.x;
  const int t = threadIdx.x;

  gbuf[t] = unmapf(gU[gi * D + t]);
  __syncthreads();

  float a = fcb1[t];
#pragma unroll
  for (int k = 0; k < 64; ++k) a = fmaf(gbuf[k], fcW1[k * 64 + t], a);
  hid[t] = fmaxf(a, 0.0f);
  __syncthreads();

  if (t < N_CLASSES) {
    float l = fcb2[t];
#pragma unroll
    for (int k = 0; k < 64; ++k) l = fmaf(hid[k], fcW2[k * N_CLASSES + t], l);
    logit[t] = l;
  }
  __syncthreads();

  if (t == 0) {
    float mx = logit[0];
    for (int i = 1; i < N_CLASSES; ++i) mx = fmaxf(mx, logit[i]);
    float s = 0.0f;
    for (int i = 0; i < N_CLASSES; ++i) s += expf(logit[i] - mx);
    red[0] = mx;
    red[1] = logf(s);
  }
  __syncthreads();

  if (t < N_CLASSES) out[gi * N_CLASSES + t] = logit[t] - red[0] - red[1];
}

// ---------------- launch ----------------

extern "C" void kernel_launch(void* const* d_in, const int* in_sizes, int n_in,
                              void* d_out, int out_size, void* d_ws, size_t ws_size,
                              hipStream_t stream) {
  const float* x      = (const float*)d_in[0];
  const float* convW1 = (const float*)d_in[1];
  const float* convb1 = (const float*)d_in[2];
  const float* convW2 = (const float*)d_in[3];
  const float* convb2 = (const float*)d_in[4];
  const float* fcW1   = (const float*)d_in[5];
  const float* fcb1   = (const float*)d_in[6];
  const float* fcW2   = (const float*)d_in[7];
  const float* fcb2   = (const float*)d_in[8];
  const int*   edge   = (const int*)d_in[9];
  const int*   batch  = (const int*)d_in[10];
  float* out = (float*)d_out;

  const int* src = edge;
  const int* dst = edge + N_EDGES;

  // workspace layout (~16.5 MB)
  unsigned* xb  = (unsigned*)d_ws;                  // 6.4 MB bf16 h (h0, h2)
  unsigned* hbA = xb + (size_t)N_NODES * 32;        // 6.4 MB bf16 h (agg out / h1)
  unsigned* gU  = hbA + (size_t)N_NODES * 32;       // 131 KB
  int* rs  = (int*)(gU + N_GRAPHS * D);             // 200 KB
  int* csr = rs + N_NODES + 1;                      // 3.2 MB
  ushort* wf = (ushort*)(csr + N_EDGES);            // 96 KB
  // deg/cur/bsum overlap hbA (dead before hbA is first written by layer-1 agg)
  int* deg  = (int*)hbA;
  int* cur  = deg + N_NODES;
  int* bsum = cur + N_NODES;

  // ---- prep: x->bf16, W fragments, pool init ----
  to_bf16<<<(N_NODES * 16) / 256, 256, 0, stream>>>(x, xb);
  wprep<<<6, 512, 0, stream>>>(convW1, convW2, wf);
  init_g<<<(N_GRAPHS * D + 255) / 256, 256, 0, stream>>>(gU);

  // ---- CSR build (dst-indexed) ----
  hipMemsetAsync(deg, 0, N_NODES * sizeof(int), stream);
  hist_kernel<<<N_EDGES / 256, 256, 0, stream>>>(dst, deg);
  scan_blocks<<<NB_SCAN, SCAN_B, 0, stream>>>(deg, bsum);
  scan_mid<<<1, 256, 0, stream>>>(bsum);
  scan_final<<<NB_SCAN, SCAN_B, 0, stream>>>(deg, bsum, rs, cur);
  fill_csr<<<N_EDGES / 256, 256, 0, stream>>>(src, dst, cur, csr);

  // ---- 3 GIN layers (agg out-of-place, mlp in-place) ----
  const int AGG_B = N_NODES / 8;    // 6250
  const int MLP_B = (NT + 3) / 4;   // 782
  agg_bf16<<<AGG_B, 256, 0, stream>>>(xb, csr, rs, hbA);
  mlp_bf16<0><<<MLP_B, 256, 0, stream>>>(hbA, wf, convb1, convb2, batch, gU);
  agg_bf16<<<AGG_B, 256, 0, stream>>>(hbA, csr, rs, xb);
  mlp_bf16<0><<<MLP_B, 256, 0, stream>>>(xb, wf + 16384, convb1 + 64, convb2 + 64,
                                         batch, gU);
  agg_bf16<<<AGG_B, 256, 0, stream>>>(xb, csr, rs, hbA);
  mlp_bf16<1><<<MLP_B, 256, 0, stream>>>(hbA, wf + 32768, convb1 + 128, convb2 + 128,
                                         batch, gU);

  // ---- FC head + log_softmax ----
  head_kernel<<<N_GRAPHS, 64, 0, stream>>>(gU, fcW1, fcb1, fcW2, fcb2, out);
}

// Round 8
// 228.733 us; speedup vs baseline: 1.7911x; 1.0608x over previous
//
#include <hip/hip_runtime.h>
#include <math.h>

#define N_NODES 50000
#define N_EDGES 800000
#define D 64
#define N_GRAPHS 512
#define N_CLASSES 10
#define NT 3125        // 16-row tiles
#define NPART 6250     // nodes per XCD partition (50000/8)

#define SCAN_B 512
#define NB_SCAN ((N_NODES + SCAN_B - 1) / SCAN_B)  // 98

typedef __attribute__((ext_vector_type(8))) short bf16x8;
typedef __attribute__((ext_vector_type(4))) float f32x4;

#define MFMA16(a, b, c) __builtin_amdgcn_mfma_f32_16x16x32_bf16(a, b, c, 0, 0, 0)

// ---------------- helpers ----------------

__device__ __forceinline__ unsigned mapf(float f) {
  unsigned u = __float_as_uint(f);
  return (u & 0x80000000u) ? ~u : (u | 0x80000000u);
}
__device__ __forceinline__ float unmapf(unsigned u) {
  return __uint_as_float((u & 0x80000000u) ? (u & 0x7FFFFFFFu) : ~u);
}
__device__ __forceinline__ ushort bf16_rne(float f) {
  unsigned u = __float_as_uint(f);
  u += 0x7FFFu + ((u >> 16) & 1u);
  return (ushort)(u >> 16);
}
__device__ __forceinline__ float bf16_tof(ushort h) {
  return __uint_as_float(((unsigned)h) << 16);
}
__device__ __forceinline__ unsigned pack2(float a, float b) {
  return (unsigned)bf16_rne(a) | ((unsigned)bf16_rne(b) << 16);
}
__device__ __forceinline__ float2 unpack2(unsigned v) {
  return make_float2(__uint_as_float(v << 16), __uint_as_float(v & 0xFFFF0000u));
}

// ---------------- x -> bf16 ----------------

__global__ void to_bf16(const float* __restrict__ in, unsigned* __restrict__ out) {
  int i = blockIdx.x * 256 + threadIdx.x;  // one float4 -> uint2 per thread
  float4 v = reinterpret_cast<const float4*>(in)[i];
  reinterpret_cast<uint2*>(out)[i] = make_uint2(pack2(v.x, v.y), pack2(v.z, v.w));
}

// ---------------- weight fragment prep (hi/lo split) ----------------
// wf layout (ushorts): per layer 16384: W1hi@0, W1lo@4096, W2hi@8192, W2lo@12288.
// within region: frag f (8), lane (64), v (8): off = f*512 + lane*8 + v
// value = W[k][n], k = (f&1)*32 + (lane>>4)*8 + v, n = (f>>1)*16 + (lane&15)

__global__ void wprep(const float* __restrict__ convW1, const float* __restrict__ convW2,
                      ushort* __restrict__ wf) {
  const int wi = blockIdx.x;  // 0..5 = layer*2 + which
  const int layer = wi >> 1, which = wi & 1;
  const float* W = (which ? convW2 : convW1) + layer * 4096;
  const int t = threadIdx.x;  // 0..511
  const int f = t >> 6, lane = t & 63;
  const int ct = f >> 1, ks = f & 1;
  const int n = ct * 16 + (lane & 15);
  const int k0 = ks * 32 + ((lane >> 4) << 3);
  ushort hi[8], lo[8];
#pragma unroll
  for (int v = 0; v < 8; ++v) {
    float w = W[(k0 + v) * 64 + n];
    ushort h = bf16_rne(w);
    hi[v] = h;
    lo[v] = bf16_rne(w - bf16_tof(h));
  }
  ushort* base = wf + layer * 16384 + which * 8192;
  *(uint4*)(base + f * 512 + lane * 8) = *(uint4*)hi;
  *(uint4*)(base + 4096 + f * 512 + lane * 8) = *(uint4*)lo;
}

// ---------------- CSR build (XCD-partitioned writes) ----------------
// partition p = blockIdx.x & 7 owns dst in [p*NPART, (p+1)*NPART): all deg/cur/csr
// lines written by one XCD's L2 only -> no cross-XCD partial-line thrash.

__global__ void hist_part(const int* __restrict__ dst, int* __restrict__ deg) {
  const int p = blockIdx.x & 7;
  const int lo = p * NPART, hi = lo + NPART;
  const int stride = (gridDim.x >> 3) * 256;
  for (int e = (blockIdx.x >> 3) * 256 + threadIdx.x; e < N_EDGES; e += stride) {
    int d = dst[e];
    if (d >= lo && d < hi) atomicAdd(&deg[d], 1);
  }
}

__global__ void scan_blocks(const int* __restrict__ deg, int* __restrict__ bsum) {
  __shared__ int sd[SCAN_B];
  int i = blockIdx.x * SCAN_B + threadIdx.x;
  sd[threadIdx.x] = (i < N_NODES) ? deg[i] : 0;
  __syncthreads();
  for (int off = SCAN_B / 2; off > 0; off >>= 1) {
    if (threadIdx.x < off) sd[threadIdx.x] += sd[threadIdx.x + off];
    __syncthreads();
  }
  if (threadIdx.x == 0) bsum[blockIdx.x] = sd[0];
}

__global__ void scan_mid(int* __restrict__ bsum) {
  __shared__ int s[256];
  int t = threadIdx.x;
  if (t < NB_SCAN) s[t] = bsum[t];
  __syncthreads();
  if (t == 0) {
    int run = 0;
    for (int i = 0; i < NB_SCAN; ++i) { int v = s[i]; s[i] = run; run += v; }
  }
  __syncthreads();
  if (t < NB_SCAN) bsum[t] = s[t];
}

__global__ void scan_final(const int* __restrict__ deg, const int* __restrict__ bsum,
                           int* __restrict__ rs, int* __restrict__ cur) {
  __shared__ int sd[SCAN_B];
  int i = blockIdx.x * SCAN_B + threadIdx.x;
  int v = (i < N_NODES) ? deg[i] : 0;
  sd[threadIdx.x] = v;
  __syncthreads();
  for (int off = 1; off < SCAN_B; off <<= 1) {
    int add = (threadIdx.x >= off) ? sd[threadIdx.x - off] : 0;
    __syncthreads();
    sd[threadIdx.x] += add;
    __syncthreads();
  }
  if (i < N_NODES) {
    int ex = bsum[blockIdx.x] + sd[threadIdx.x] - v;
    rs[i] = ex;
    cur[i] = ex;
  }
  if (i == 0) rs[N_NODES] = N_EDGES;
}

__global__ void fill_part(const int* __restrict__ src, const int* __restrict__ dst,
                          int* __restrict__ cur, int* __restrict__ csr) {
  const int p = blockIdx.x & 7;
  const int lo = p * NPART, hi = lo + NPART;
  const int stride = (gridDim.x >> 3) * 256;
  for (int e = (blockIdx.x >> 3) * 256 + threadIdx.x; e < N_EDGES; e += stride) {
    int d = dst[e];
    if (d >= lo && d < hi) {
      int pos = atomicAdd(&cur[d], 1);
      csr[pos] = src[e];
    }
  }
}

// ---------------- GIN aggregation: out[n] = bf16( h[n] + sum h[csr[e]] ) ----------------

__global__ __launch_bounds__(256) void agg_bf16(
    const unsigned* __restrict__ hin, const int* __restrict__ csr,
    const int* __restrict__ rs, unsigned* __restrict__ hout) {
  const int t = threadIdx.x;
  const int hw = t >> 5, hl = t & 31;
  const int node = blockIdx.x * 8 + hw;
  float2 a = unpack2(hin[node * 32 + hl]);  // self term
  int e = rs[node];
  const int e1 = rs[node + 1];
  for (; e + 4 <= e1; e += 4) {
    int s0 = csr[e], s1 = csr[e + 1], s2 = csr[e + 2], s3 = csr[e + 3];
    float2 v0 = unpack2(hin[s0 * 32 + hl]);
    float2 v1 = unpack2(hin[s1 * 32 + hl]);
    float2 v2 = unpack2(hin[s2 * 32 + hl]);
    float2 v3 = unpack2(hin[s3 * 32 + hl]);
    a.x += v0.x + v1.x; a.y += v0.y + v1.y;
    a.x += v2.x + v3.x; a.y += v2.y + v3.y;
  }
  for (; e < e1; ++e) {
    float2 v = unpack2(hin[csr[e] * 32 + hl]);
    a.x += v.x; a.y += v.y;
  }
  hout[node * 32 + hl] = pack2(a.x, a.y);
}

// ---------------- MFMA MLP (bf16): Aout = relu(Ain@W1+b1)@W2+b2 ----------------
// Out-of-place. All weights (32KB) staged once; ONE barrier. Coalesced output
// via per-wave LDS bounce (lane l stores bytes [32l,32l+32) of the 2KB tile).
// A-frag: lane row=lane&15, k=(ks*32)+(lane>>4)*8+v. C/D: col=lane&15, row=(lane>>4)*4+j.

template <int FINAL>
__global__ __launch_bounds__(256, 2) void mlp_bf16(
    const unsigned* __restrict__ Ain,   // bf16 rows
    unsigned* __restrict__ Aout,        // bf16 rows (FINAL: unused)
    const ushort* __restrict__ wfL,     // layer base (16384 ushorts)
    const float* __restrict__ b1, const float* __restrict__ b2,
    const int* __restrict__ batch, unsigned* __restrict__ gU) {
  __shared__ ushort Wl[16384];       // 32KB: W1hi@0 W1lo@8KB W2hi@16KB W2lo@24KB (bytes)
  __shared__ ushort tb[4][16 * 72];  // per-wave transpose buf
  const int t = threadIdx.x;
  const int w = t >> 6, lane = t & 63;
  const int tile = blockIdx.x * 4 + w;
  const bool act = (tile < NT);
  const int m = lane & 15, g = lane >> 4;
  ushort* tw = tb[w];

  // ---- stage W1+W2 hi/lo (32KB) once ----
  {
    const uint4* s = (const uint4*)wfL;
    uint4* d = (uint4*)Wl;
#pragma unroll
    for (int i = 0; i < 8; ++i) d[t + 256 * i] = s[t + 256 * i];
  }

  // ---- A fragments: exact bf16 loads (row = m, k = ks*32 + g*8 + v) ----
  bf16x8 a0 = {}, a1 = {};
  if (act) {
    const ushort* Ar = (const ushort*)Ain + (size_t)(tile * 16 + m) * 64;
    a0 = *(const bf16x8*)(Ar + g * 8);
    a1 = *(const bf16x8*)(Ar + 32 + g * 8);
  }
  __syncthreads();  // the only block-wide barrier

  const char* wb = (const char*)Wl + lane * 16;
#define LDW(off) (*(const bf16x8*)(wb + (off)))

  if (act) {
    // ---- GEMM1: c = A@(W1hi + W1lo) ----
    f32x4 c0 = {0.f, 0.f, 0.f, 0.f}, c1 = c0, c2 = c0, c3 = c0;
#define G1(ct, cc)                                        \
    cc = MFMA16(a0, LDW((2 * ct + 0) * 1024), cc);        \
    cc = MFMA16(a1, LDW((2 * ct + 1) * 1024), cc);        \
    cc = MFMA16(a0, LDW(8192 + (2 * ct + 0) * 1024), cc); \
    cc = MFMA16(a1, LDW(8192 + (2 * ct + 1) * 1024), cc);
    G1(0, c0) G1(1, c1) G1(2, c2) G1(3, c3)
#undef G1

    // ---- bias + relu -> bf16 transpose (C/D -> A-frag layout) ----
    float bv0 = b1[m], bv1 = b1[16 + m], bv2 = b1[32 + m], bv3 = b1[48 + m];
#define WRT(cc, ct, bv)                                                     \
    tw[(g * 4 + 0) * 72 + ct * 16 + m] = bf16_rne(fmaxf(cc[0] + bv, 0.f));  \
    tw[(g * 4 + 1) * 72 + ct * 16 + m] = bf16_rne(fmaxf(cc[1] + bv, 0.f));  \
    tw[(g * 4 + 2) * 72 + ct * 16 + m] = bf16_rne(fmaxf(cc[2] + bv, 0.f));  \
    tw[(g * 4 + 3) * 72 + ct * 16 + m] = bf16_rne(fmaxf(cc[3] + bv, 0.f));
    WRT(c0, 0, bv0) WRT(c1, 1, bv1) WRT(c2, 2, bv2) WRT(c3, 3, bv3)
#undef WRT
    bf16x8 h0 = *(const bf16x8*)(tw + m * 72 + g * 8);
    bf16x8 h1 = *(const bf16x8*)(tw + m * 72 + 32 + g * 8);

    // ---- GEMM2: c = H@(W2hi + W2lo) ----
    c0 = (f32x4){0.f, 0.f, 0.f, 0.f}; c1 = c0; c2 = c0; c3 = c0;
#define G2(ct, cc)                                         \
    cc = MFMA16(h0, LDW(16384 + (2 * ct + 0) * 1024), cc); \
    cc = MFMA16(h1, LDW(16384 + (2 * ct + 1) * 1024), cc); \
    cc = MFMA16(h0, LDW(24576 + (2 * ct + 0) * 1024), cc); \
    cc = MFMA16(h1, LDW(24576 + (2 * ct + 1) * 1024), cc);
    G2(0, c0) G2(1, c1) G2(2, c2) G2(3, c3)
#undef G2
#undef LDW

    float bv20 = b2[m], bv21 = b2[16 + m], bv22 = b2[32 + m], bv23 = b2[48 + m];
    if (FINAL) {
      int b40 = batch[tile * 16 + g * 4 + 0];
      int b41 = batch[tile * 16 + g * 4 + 1];
      int b42 = batch[tile * 16 + g * 4 + 2];
      int b43 = batch[tile * 16 + g * 4 + 3];
#define PM(cc, ct, bv)                                          \
      atomicMax(&gU[b40 * 64 + ct * 16 + m], mapf(cc[0] + bv)); \
      atomicMax(&gU[b41 * 64 + ct * 16 + m], mapf(cc[1] + bv)); \
      atomicMax(&gU[b42 * 64 + ct * 16 + m], mapf(cc[2] + bv)); \
      atomicMax(&gU[b43 * 64 + ct * 16 + m], mapf(cc[3] + bv));
      PM(c0, 0, bv20) PM(c1, 1, bv21) PM(c2, 2, bv22) PM(c3, 3, bv23)
#undef PM
    } else {
      // bias -> bf16 into tb, then fully-coalesced stores: lane l owns 32B chunk l
#define WRO(cc, ct, bv)                                          \
      tw[(g * 4 + 0) * 72 + ct * 16 + m] = bf16_rne(cc[0] + bv); \
      tw[(g * 4 + 1) * 72 + ct * 16 + m] = bf16_rne(cc[1] + bv); \
      tw[(g * 4 + 2) * 72 + ct * 16 + m] = bf16_rne(cc[2] + bv); \
      tw[(g * 4 + 3) * 72 + ct * 16 + m] = bf16_rne(cc[3] + bv);
      WRO(c0, 0, bv20) WRO(c1, 1, bv21) WRO(c2, 2, bv22) WRO(c3, 3, bv23)
#undef WRO
      const int r = lane >> 2, q = lane & 3;  // row r, 16-ushort chunk q
      uint4 v0 = *(const uint4*)(tw + r * 72 + q * 16);
      uint4 v1 = *(const uint4*)(tw + r * 72 + q * 16 + 8);
      ushort* Ao = (ushort*)Aout + (size_t)tile * 1024;
      *(uint4*)(Ao + lane * 16) = v0;
      *(uint4*)(Ao + lane * 16 + 8) = v1;
    }
  }
}

// ---------------- pooling init + head ----------------

__global__ void init_g(unsigned* __restrict__ gU) {
  int i = blockIdx.x * blockDim.x + threadIdx.x;
  if (i < N_GRAPHS * D) gU[i] = 0x007FFFFFu;  // mapf(-inf)
}

__global__ void head_kernel(const unsigned* __restrict__ gU,
                            const float* __restrict__ fcW1, const float* __restrict__ fcb1,
                            const float* __restrict__ fcW2, const float* __restrict__ fcb2,
                            float* __restrict__ out) {
  __shared__ float gbuf[64];
  __shared__ float hid[64];
  __shared__ float logit[N_CLASSES];
  __shared__ float red[2];
  const int gi = blockIdx.x;
  const int t = threadIdx.x;

  gbuf[t] = unmapf(gU[gi * D + t]);
  __syncthreads();

  float a = fcb1[t];
#pragma unroll
  for (int k = 0; k < 64; ++k) a = fmaf(gbuf[k], fcW1[k * 64 + t], a);
  hid[t] = fmaxf(a, 0.0f);
  __syncthreads();

  if (t < N_CLASSES) {
    float l = fcb2[t];
#pragma unroll
    for (int k = 0; k < 64; ++k) l = fmaf(hid[k], fcW2[k * N_CLASSES + t], l);
    logit[t] = l;
  }
  __syncthreads();

  if (t == 0) {
    float mx = logit[0];
    for (int i = 1; i < N_CLASSES; ++i) mx = fmaxf(mx, logit[i]);
    float s = 0.0f;
    for (int i = 0; i < N_CLASSES; ++i) s += expf(logit[i] - mx);
    red[0] = mx;
    red[1] = logf(s);
  }
  __syncthreads();

  if (t < N_CLASSES) out[gi * N_CLASSES + t] = logit[t] - red[0] - red[1];
}

// ---------------- launch ----------------

extern "C" void kernel_launch(void* const* d_in, const int* in_sizes, int n_in,
                              void* d_out, int out_size, void* d_ws, size_t ws_size,
                              hipStream_t stream) {
  const float* x      = (const float*)d_in[0];
  const float* convW1 = (const float*)d_in[1];
  const float* convb1 = (const float*)d_in[2];
  const float* convW2 = (const float*)d_in[3];
  const float* convb2 = (const float*)d_in[4];
  const float* fcW1   = (const float*)d_in[5];
  const float* fcb1   = (const float*)d_in[6];
  const float* fcW2   = (const float*)d_in[7];
  const float* fcb2   = (const float*)d_in[8];
  const int*   edge   = (const int*)d_in[9];
  const int*   batch  = (const int*)d_in[10];
  float* out = (float*)d_out;

  const int* src = edge;
  const int* dst = edge + N_EDGES;

  // workspace layout (~23 MB)
  unsigned* xb  = (unsigned*)d_ws;                  // 6.4 MB bf16 h
  unsigned* hbA = xb + (size_t)N_NODES * 32;        // 6.4 MB bf16 (agg out)
  unsigned* hbB = hbA + (size_t)N_NODES * 32;       // 6.4 MB bf16 (mlp out)
  unsigned* gU  = hbB + (size_t)N_NODES * 32;       // 131 KB
  int* rs  = (int*)(gU + N_GRAPHS * D);             // 200 KB
  int* csr = rs + N_NODES + 1;                      // 3.2 MB
  ushort* wf = (ushort*)(csr + N_EDGES);            // 96 KB
  // deg/cur/bsum overlap hbB (dead before hbB is first written by mlp #1)
  int* deg  = (int*)hbB;
  int* cur  = deg + N_NODES;
  int* bsum = cur + N_NODES;

  // ---- prep: x->bf16, W fragments, pool init ----
  to_bf16<<<(N_NODES * 16) / 256, 256, 0, stream>>>(x, xb);
  wprep<<<6, 512, 0, stream>>>(convW1, convW2, wf);
  init_g<<<(N_GRAPHS * D + 255) / 256, 256, 0, stream>>>(gU);

  // ---- CSR build (dst-indexed, XCD-partitioned writes) ----
  hipMemsetAsync(deg, 0, N_NODES * sizeof(int), stream);
  hist_part<<<2048, 256, 0, stream>>>(dst, deg);
  scan_blocks<<<NB_SCAN, SCAN_B, 0, stream>>>(deg, bsum);
  scan_mid<<<1, 256, 0, stream>>>(bsum);
  scan_final<<<NB_SCAN, SCAN_B, 0, stream>>>(deg, bsum, rs, cur);
  fill_part<<<2048, 256, 0, stream>>>(src, dst, cur, csr);

  // ---- 3 GIN layers: agg X->T, mlp T->Y, swap ----
  const int AGG_B = N_NODES / 8;    // 6250
  const int MLP_B = (NT + 3) / 4;   // 782
  agg_bf16<<<AGG_B, 256, 0, stream>>>(xb, csr, rs, hbA);
  mlp_bf16<0><<<MLP_B, 256, 0, stream>>>(hbA, hbB, wf, convb1, convb2, batch, gU);
  agg_bf16<<<AGG_B, 256, 0, stream>>>(hbB, csr, rs, hbA);
  mlp_bf16<0><<<MLP_B, 256, 0, stream>>>(hbA, xb, wf + 16384, convb1 + 64, convb2 + 64,
                                         batch, gU);
  agg_bf16<<<AGG_B, 256, 0, stream>>>(xb, csr, rs, hbA);
  mlp_bf16<1><<<MLP_B, 256, 0, stream>>>(hbA, nullptr, wf + 32768, convb1 + 128,
                                         convb2 + 128, batch, gU);

  // ---- FC head + log_softmax ----
  head_kernel<<<N_GRAPHS, 64, 0, stream>>>(gU, fcW1, fcb1, fcW2, fcb2, out);
}